// Round 4
// baseline (5220.061 us; speedup 1.0000x reference)
//
#include <hip/hip_runtime.h>
#include <math.h>

// Problem constants
#define B_ROWS 8192
#define S_LEN  512
#define H_DIM  256
#define G3     768          // 3*H
#define P_DIM  96
#define TB     32           // batch rows per block

typedef __attribute__((ext_vector_type(8))) _Float16 half8;  // 8 f16 (4 VGPRs)
typedef __attribute__((ext_vector_type(4))) float floatx4;   // MFMA C/D frag

__device__ __forceinline__ float sigmoid_fast(float v) {
    return 1.0f / (1.0f + __expf(-v));
}
__device__ __forceinline__ float tanh_fast(float v) {
    return 1.0f - 2.0f / (__expf(2.0f * v) + 1.0f);
}
__device__ __forceinline__ unsigned short f32_f16(float f) {
    _Float16 h = (_Float16)f;                 // RTN
    return __builtin_bit_cast(unsigned short, h);
}
// Involutive 6-bit lane rotation: spreads scatter dest-lanes across bank groups.
__device__ __forceinline__ int rot3(int l) { return ((l << 3) | (l >> 3)) & 63; }

// -------- One-time weight pack: W_hh -> per-lane MFMA B-fragments (hi/lo fp16).
// h in (-1,1) is sent as SINGLE fp16; W is split hi+lo fp16 (~2^-22 capture).
// B[k][n] = W_hh[n][k].  16x16x32 B-frag: lane holds B[n=lane&15][k=quad*8+j].
// Tile index = (k>>5)*48 + (j>>4); lane = (j&15) | (((k>>3)&3)<<4); short = k&7.
// Also WoT[k][p] = W_out[p][k]; also zeroes the (now unused) sync counter.
__global__ void pack_weights(const float* __restrict__ W_hh,
                             const float* __restrict__ W_out,
                             unsigned short* __restrict__ Bh,
                             unsigned short* __restrict__ Bl,
                             float* __restrict__ WoT,
                             unsigned int* __restrict__ ctr) {
    const int j = blockIdx.x;    // gate col 0..767
    const int k = threadIdx.x;   // h idx   0..255
    const float wv = W_hh[j * H_DIM + k];
    const unsigned short hi = f32_f16(wv);
    const float hf = (float)__builtin_bit_cast(_Float16, hi);
    const unsigned short lo = f32_f16(wv - hf);
    const int idx = (((k >> 5) * 48 + (j >> 4)) * 64 +
                     ((j & 15) | (((k >> 3) & 3) << 4))) * 8 + (k & 7);
    Bh[idx] = hi;
    Bl[idx] = lo;
    if (j < P_DIM) WoT[k * P_DIM + j] = W_out[j * H_DIM + k];
    if (j == 0 && k == 0) *ctr = 0u;   // d_ws is re-poisoned every launch
}

// LDS layout (132 KiB total):
//   [0,       32768)  A-fragments (fp16), double-buffered:
//                     buf*16384 + chunk(kc*2+mt)*1024 + slot*16 + short*2
//                     (slot = rot3'd fragment-lane index)
//   [32768,   36864)  xtile[2][32][16] fp32
//   [36864,  135168)  W cache: 96 tiles x 1 KiB = kc=6 hi (slots 0..47,
//                     index T=(gh>>1)*16+w*2+(gh&1)) and kc=6 lo (48..95)
#define A_OFF   0
#define X_OFF   32768
#define W_OFF   36864
#define LDS_SZ  135168

__device__ __forceinline__ void mfma2(floatx4& c0, floatx4& c1,
                                      const half8& a0, const half8& a1,
                                      const half8& bh, const half8& bl) {
    c0 = __builtin_amdgcn_mfma_f32_16x16x32_f16(a0, bh, c0, 0, 0, 0);
    c1 = __builtin_amdgcn_mfma_f32_16x16x32_f16(a1, bh, c1, 0, 0, 0);
    c0 = __builtin_amdgcn_mfma_f32_16x16x32_f16(a0, bl, c0, 0, 0, 0);
    c1 = __builtin_amdgcn_mfma_f32_16x16x32_f16(a1, bl, c1, 0, 0, 0);
}

// Issue 12 streamed tile loads for one kc (element offset koff = kc*24576).
__device__ __forceinline__ void gissue(half8 (&BH)[6], half8 (&BL)[6],
                                       const unsigned short* (&pbh)[6],
                                       const unsigned short* (&pbl)[6],
                                       size_t koff) {
#pragma unroll
    for (int gh = 0; gh < 6; ++gh) {
        BH[gh] = *(const half8*)(pbh[gh] + koff);
        BL[gh] = *(const half8*)(pbl[gh] + koff);
    }
}

__device__ __forceinline__ void ahread(half8 (&AH)[2], const char* Ac,
                                       int kc, int rl) {
#pragma unroll
    for (int mt = 0; mt < 2; ++mt)
        AH[mt] = *(const half8*)(Ac + (kc * 2 + mt) * 1024 + rl * 16);
}

__device__ __forceinline__ void kcmfma(floatx4 (&acc)[3][2][2],
                                       const half8 (&AH)[2],
                                       const half8 (&BH)[6],
                                       const half8 (&BL)[6]) {
#pragma unroll
    for (int gh = 0; gh < 6; ++gh)
        mfma2(acc[gh >> 1][0][gh & 1], acc[gh >> 1][1][gh & 1],
              AH[0], AH[1], BH[gh], BL[gh]);
}

// Main persistent GRU kernel: fp16 single-A / split-W MFMA.
// Stream pipeline: 3 register buffers, prefetch distance 2 kc-blocks;
// next step's first two kc are issued before the gate phase + barrier.
// Per-CU kc-order rotation ((blockIdx>>3)%6) de-phases the L2 weight
// streams of CUs sharing an XCD (accumulation order commutes).
// grid = 256 (1 block/CU, forced by 132 KiB LDS), block = 512 (8 waves).
__global__ __launch_bounds__(512, 2)
void gru_mfma(const float* __restrict__ x,
              const float* __restrict__ W_ih,
              const float* __restrict__ b_ih,
              const float* __restrict__ b_hh,
              const unsigned short* __restrict__ Bh,
              const unsigned short* __restrict__ Bl,
              const float* __restrict__ WoT,   // [256][96]
              const float* __restrict__ b_out,
              float* __restrict__ out,
              unsigned int* __restrict__ ctr) {
    __shared__ __align__(16) char smem[LDS_SZ];

    const int tid  = threadIdx.x;
    const int w    = tid >> 6;     // wave 0..7
    const int lane = tid & 63;
    const int q    = lane >> 4;    // quad
    const int c    = lane & 15;
    const int row0 = blockIdx.x * TB;

    // Streamed-kc rotation: CUs in one XCD (blockIdx % 8 == xcd) get
    // different start offsets -> their L2 request streams de-phase.
    const int ro  = (int)((blockIdx.x >> 3) % 6u);
    const int kv0 = ro;
    const int kv1 = (ro + 1) % 6;
    const int kv2 = (ro + 2) % 6;
    const int kv3 = (ro + 3) % 6;
    const int kv4 = (ro + 4) % 6;
    const int kv5 = (ro + 5) % 6;
    const size_t o0 = (size_t)kv0 * 24576, o1 = (size_t)kv1 * 24576;
    const size_t o2 = (size_t)kv2 * 24576, o3 = (size_t)kv3 * 24576;
    const size_t o4 = (size_t)kv4 * 24576, o5 = (size_t)kv5 * 24576;

    // Per-thread gate params; col = 256*g + 32*w + 16*ht + c
    float wih[3][2], bcc[2][2], bihn[2], bhhn[2];
#pragma unroll
    for (int g = 0; g < 3; ++g)
#pragma unroll
        for (int ht = 0; ht < 2; ++ht) {
            const int col = g * H_DIM + w * 32 + ht * 16 + c;
            wih[g][ht] = W_ih[col];
            if (g < 2) {
                bcc[g][ht] = b_ih[col] + b_hh[col];
            } else {
                bihn[ht] = b_ih[col];
                bhhn[ht] = b_hh[col];
            }
        }

    // Streamed-tile base pointers (per wave/lane), gh = g*2 + ht.
    const unsigned short* pbh[6];
    const unsigned short* pbl[6];
#pragma unroll
    for (int gh = 0; gh < 6; ++gh) {
        const size_t toff = (size_t)((gh >> 1) * 16 + w * 2 + (gh & 1)) * 512 + lane * 8;
        pbh[gh] = Bh + toff;
        pbl[gh] = Bl + toff;
    }

    // Register-resident weight tiles: kc=7 hi+lo.  (48 VGPRs)
    half8 r7h[6], r7l[6];
#pragma unroll
    for (int gh = 0; gh < 6; ++gh) {
        r7h[gh] = *(const half8*)(pbh[gh] + 7 * 24576);
        r7l[gh] = *(const half8*)(pbl[gh] + 7 * 24576);
    }

    // LDS weight cache staging: 96 tiles = kc=6 hi (0..47) + kc=6 lo (48..95).
    for (int i = tid; i < 96 * 64; i += 512) {
        const int slot = i >> 6, l16 = i & 63;
        const unsigned short* src = (slot < 48)
            ? (Bh + (size_t)(288 + slot) * 512 + l16 * 8)
            : (Bl + (size_t)(288 + slot - 48) * 512 + l16 * 8);
        *(uint4*)(smem + W_OFF + slot * 1024 + l16 * 16) = *(const uint4*)src;
    }

    // Zero both A-frag buffers (h0 = 0) and stage x for t=0..15.
    for (int i = tid; i < 8192; i += 512) ((int*)(smem + A_OFF))[i] = 0;
    float* xt = (float*)(smem + X_OFF);
    {
        const int r = tid >> 4, t2 = tid & 15;
        xt[r * 16 + t2] = x[(size_t)(row0 + r) * S_LEN + t2];
    }
    __syncthreads();

    // h_old in C-frag layout: element (mt,ht,reg) = h[4q+reg+16mt][32w+16ht+c]
    float h_own[2][2][4];
#pragma unroll
    for (int mt = 0; mt < 2; ++mt)
#pragma unroll
        for (int ht = 0; ht < 2; ++ht)
#pragma unroll
            for (int r = 0; r < 4; ++r) h_own[mt][ht][r] = 0.0f;

    const int rl = rot3(lane);

    // Pipeline buffers (static names only — rule: no runtime indexing).
    half8 b0h[6], b0l[6], b1h[6], b1l[6], b2h[6], b2l[6];
    half8 ahA[2], ahB[2];

    // Prologue: first two streamed kc of step 0 in flight before the loop.
    gissue(b0h, b0l, pbh, pbl, o0);
    gissue(b1h, b1l, pbh, pbl, o1);

#pragma unroll 1
    for (int t = 0; t < S_LEN; ++t) {
        // Defeat LICM of the (t-invariant) streamed loads: make the stream
        // pointers opaque each iteration so loads stay inside the loop.
#pragma unroll
        for (int gh = 0; gh < 6; ++gh)
            asm volatile("" : "+v"(pbh[gh]), "+v"(pbl[gh]));

        const int cur = t & 1, nxt = cur ^ 1;
        const char* Ac = smem + A_OFF + cur * 16384;

        ahread(ahA, Ac, kv0, rl);          // A-frags for stage 0

        // x for my 8 rows (LDS broadcast)
        float xr[2][4];
#pragma unroll
        for (int mt = 0; mt < 2; ++mt)
#pragma unroll
            for (int r = 0; r < 4; ++r)
                xr[mt][r] = xt[(((t >> 4) & 1) * 32 + q * 4 + r + 16 * mt) * 16 + (t & 15)];

        // C frags [gate][mt][ht]; fold x-side pre-activation + bias into init.
        floatx4 acc[3][2][2];
#pragma unroll
        for (int mt = 0; mt < 2; ++mt)
#pragma unroll
            for (int ht = 0; ht < 2; ++ht)
#pragma unroll
                for (int r = 0; r < 4; ++r) {
                    acc[0][mt][ht][r] = fmaf(xr[mt][r], wih[0][ht], bcc[0][ht]);
                    acc[1][mt][ht][r] = fmaf(xr[mt][r], wih[1][ht], bcc[1][ht]);
                    acc[2][mt][ht][r] = bhhn[ht];
                }

        // ---- Pipelined ladder: buffers rotate b0,b1,b2; distance 2 ----
        gissue(b2h, b2l, pbh, pbl, o2);
        ahread(ahB, Ac, kv1, rl);
        kcmfma(acc, ahA, b0h, b0l);                       // kv0
        gissue(b0h, b0l, pbh, pbl, o3);
        ahread(ahA, Ac, kv2, rl);
        kcmfma(acc, ahB, b1h, b1l);                       // kv1
        gissue(b1h, b1l, pbh, pbl, o4);
        ahread(ahB, Ac, kv3, rl);
        kcmfma(acc, ahA, b2h, b2l);                       // kv2
        gissue(b2h, b2l, pbh, pbl, o5);
        ahread(ahA, Ac, kv4, rl);
        kcmfma(acc, ahB, b0h, b0l);                       // kv3
        gissue(b0h, b0l, pbh, pbl, o0);    // next step's kv0 (t-invariant)
        ahread(ahB, Ac, kv5, rl);
        kcmfma(acc, ahA, b1h, b1l);                       // kv4
        gissue(b1h, b1l, pbh, pbl, o1);    // next step's kv1
        ahread(ahA, Ac, 6, rl);
        kcmfma(acc, ahB, b2h, b2l);                       // kv5

        // ---- kc6: hi+lo from the LDS cache ----
        {
            half8 w6h[6], w6l[6];
#pragma unroll
            for (int gh = 0; gh < 6; ++gh) {
                const int T = (gh >> 1) * 16 + w * 2 + (gh & 1);
                w6h[gh] = *(const half8*)(smem + W_OFF + T * 1024 + lane * 16);
                w6l[gh] = *(const half8*)(smem + W_OFF + (48 + T) * 1024 + lane * 16);
            }
            ahread(ahB, Ac, 7, rl);
            kcmfma(acc, ahA, w6h, w6l);                   // kc6
        }

        // ---- kc7: fully register-resident ----
        kcmfma(acc, ahB, r7h, r7l);                       // kc7

        // Gates + h update (in-register); scatter next A-frags (rot3-swizzled).
        char* Anx = smem + A_OFF + nxt * 16384;
#pragma unroll
        for (int mt = 0; mt < 2; ++mt) {
            char* ch = Anx + (w * 2 + mt) * 1024;         // chunk kc=w
#pragma unroll
            for (int ht = 0; ht < 2; ++ht)
#pragma unroll
                for (int r = 0; r < 4; ++r) {
                    const float rr  = sigmoid_fast(acc[0][mt][ht][r]);
                    const float zz  = sigmoid_fast(acc[1][mt][ht][r]);
                    const float inn = fmaf(xr[mt][r], wih[2][ht], bihn[ht]);
                    const float nn  = tanh_fast(fmaf(rr, acc[2][mt][ht][r], inn));
                    const float hv  = (1.0f - zz) * nn + zz * h_own[mt][ht][r];
                    h_own[mt][ht][r] = hv;
                    const int d    = (q * 4 + r) | ((2 * ht + (c >> 3)) << 4);
                    const int off  = rot3(d) * 16 + (c & 7) * 2;
                    *(unsigned short*)(ch + off) = f32_f16(hv);
                }
        }

        // Re-stage x for the next 16 steps (into the idle x buffer).
        const bool tick = ((t & 15) == 15) && (t != S_LEN - 1);
        if (tick) {
            const int r = tid >> 4, t2 = tid & 15;
            xt[((((t + 1) >> 4) & 1) * 32 + r) * 16 + t2] =
                x[(size_t)(row0 + r) * S_LEN + (t + 1) + t2];
        }
        __syncthreads();   // single barrier: next A-frags + x tile visible
    }

    // -------- Epilogue: dump final h (fp32, from registers) and project.
    float* hfin = (float*)(smem);   // reuse A region: [32][256] = 32 KiB
#pragma unroll
    for (int mt = 0; mt < 2; ++mt)
#pragma unroll
        for (int ht = 0; ht < 2; ++ht)
#pragma unroll
            for (int r = 0; r < 4; ++r) {
                const int m = q * 4 + r + 16 * mt;
                const int k = w * 32 + ht * 16 + c;
                hfin[m * H_DIM + k] = h_own[mt][ht][r];
            }
    __syncthreads();

    if (tid < 256) {
        const int cid   = tid & 63;
        const int rid   = tid >> 6;
        const int myrow = rid * 8;
        const int pA    = cid;
        const int pB    = 64 + cid;
        const bool hasB = (cid < 32);
        float accA[8], accB[8];
#pragma unroll
        for (int rr = 0; rr < 8; ++rr) { accA[rr] = 0.0f; accB[rr] = 0.0f; }

        for (int k = 0; k < H_DIM; k += 4) {
            float4 hv[8];
#pragma unroll
            for (int rr = 0; rr < 8; ++rr)
                hv[rr] = *(const float4*)&hfin[(myrow + rr) * H_DIM + k];
            float wA[4], wB[4];
#pragma unroll
            for (int kk = 0; kk < 4; ++kk) {
                wA[kk] = WoT[(size_t)(k + kk) * P_DIM + pA];
                wB[kk] = hasB ? WoT[(size_t)(k + kk) * P_DIM + pB] : 0.0f;
            }
#pragma unroll
            for (int kk = 0; kk < 4; ++kk)
#pragma unroll
                for (int rr = 0; rr < 8; ++rr) {
                    const float hvv = (&hv[rr].x)[kk];
                    accA[rr] = fmaf(hvv, wA[kk], accA[rr]);
                    accB[rr] = fmaf(hvv, wB[kk], accB[rr]);
                }
        }
        const float boA = b_out[pA];
        const float boB = hasB ? b_out[pB] : 0.0f;
#pragma unroll
        for (int rr = 0; rr < 8; ++rr) {
            const size_t orow = (size_t)(row0 + myrow + rr) * P_DIM;
            out[orow + pA] = accA[rr] + boA;
            if (hasB) out[orow + pB] = accB[rr] + boB;
        }
    }
}

// -------- fp32 fallback — used only if ws_size is too small.
__global__ __launch_bounds__(256, 1)
void gru_fallback(const float* __restrict__ x,
                  const float* __restrict__ W_ih,
                  const float* __restrict__ Whh,
                  const float* __restrict__ b_ih,
                  const float* __restrict__ b_hh,
                  const float* __restrict__ Wout,
                  const float* __restrict__ b_out,
                  float* __restrict__ out) {
    __shared__ float hbuf[2][TB][H_DIM];

    const int tid   = threadIdx.x;
    const int cid   = tid & 63;
    const int rid   = tid >> 6;
    const int row0  = blockIdx.x * TB;
    const int myrow = rid * 8;
    const int c0    = cid * 4;

    float wih[3][4], bc[2][4], bihn[4], bhhn[4];
#pragma unroll
    for (int cc = 0; cc < 4; ++cc) {
        const int j = c0 + cc;
        wih[0][cc] = W_ih[j];
        wih[1][cc] = W_ih[H_DIM + j];
        wih[2][cc] = W_ih[2 * H_DIM + j];
        bc[0][cc]  = b_ih[j] + b_hh[j];
        bc[1][cc]  = b_ih[H_DIM + j] + b_hh[H_DIM + j];
        bihn[cc]   = b_ih[2 * H_DIM + j];
        bhhn[cc]   = b_hh[2 * H_DIM + j];
    }
    for (int i = tid; i < TB * H_DIM; i += 256) (&hbuf[0][0][0])[i] = 0.0f;
    float h_own[8][4];
#pragma unroll
    for (int rr = 0; rr < 8; ++rr)
#pragma unroll
        for (int cc = 0; cc < 4; ++cc) h_own[rr][cc] = 0.0f;
    __syncthreads();

    int p = 0;
    for (int t = 0; t < S_LEN; ++t) {
        float xv[8];
#pragma unroll
        for (int rr = 0; rr < 8; ++rr)
            xv[rr] = x[(size_t)(row0 + myrow + rr) * S_LEN + t];

        float acc[3][8][4];
#pragma unroll
        for (int rr = 0; rr < 8; ++rr)
#pragma unroll
            for (int cc = 0; cc < 4; ++cc) {
                acc[0][rr][cc] = fmaf(xv[rr], wih[0][cc], bc[0][cc]);
                acc[1][rr][cc] = fmaf(xv[rr], wih[1][cc], bc[1][cc]);
                acc[2][rr][cc] = bhhn[cc];
            }
        const float* hb = &hbuf[p][0][0];
        for (int k = 0; k < H_DIM; k += 4) {
            float4 hv[8];
#pragma unroll
            for (int rr = 0; rr < 8; ++rr)
                hv[rr] = *(const float4*)(hb + (myrow + rr) * H_DIM + k);
#pragma unroll
            for (int g = 0; g < 3; ++g)
#pragma unroll
                for (int kk = 0; kk < 4; ++kk) {
                    float wrow[4];
#pragma unroll
                    for (int cc = 0; cc < 4; ++cc)
                        wrow[cc] = Whh[(size_t)(g * H_DIM + c0 + cc) * H_DIM + k + kk];
#pragma unroll
                    for (int rr = 0; rr < 8; ++rr) {
                        const float hvv = (&hv[rr].x)[kk];
#pragma unroll
                        for (int cc = 0; cc < 4; ++cc)
                            acc[g][rr][cc] = fmaf(hvv, wrow[cc], acc[g][rr][cc]);
                    }
                }
        }
#pragma unroll
        for (int rr = 0; rr < 8; ++rr) {
            float4 hnew;
#pragma unroll
            for (int cc = 0; cc < 4; ++cc) {
                const float r_  = sigmoid_fast(acc[0][rr][cc]);
                const float z_  = sigmoid_fast(acc[1][rr][cc]);
                const float i_n = fmaf(xv[rr], wih[2][cc], bihn[cc]);
                const float n_  = tanh_fast(fmaf(r_, acc[2][rr][cc], i_n));
                const float hv2 = (1.0f - z_) * n_ + z_ * h_own[rr][cc];
                h_own[rr][cc] = hv2;
                (&hnew.x)[cc] = hv2;
            }
            *(float4*)&hbuf[1 - p][myrow + rr][c0] = hnew;
        }
        __syncthreads();
        p ^= 1;
    }

    const int  pA   = cid;
    const int  pB   = 64 + cid;
    const bool hasB = (cid < 32);
    float accA[8], accB[8];
#pragma unroll
    for (int rr = 0; rr < 8; ++rr) { accA[rr] = 0.0f; accB[rr] = 0.0f; }
    for (int k = 0; k < H_DIM; k += 4) {
        float4 hv[8];
#pragma unroll
        for (int rr = 0; rr < 8; ++rr)
            hv[rr] = *(const float4*)&hbuf[p][myrow + rr][k];
        float wA[4], wB[4];
#pragma unroll
        for (int kk = 0; kk < 4; ++kk) {
            wA[kk] = Wout[(size_t)pA * H_DIM + k + kk];
            wB[kk] = hasB ? Wout[(size_t)pB * H_DIM + k + kk] : 0.0f;
        }
#pragma unroll
        for (int kk = 0; kk < 4; ++kk)
#pragma unroll
            for (int rr = 0; rr < 8; ++rr) {
                const float hvv = (&hv[rr].x)[kk];
                accA[rr] = fmaf(hvv, wA[kk], accA[rr]);
                accB[rr] = fmaf(hvv, wB[kk], accB[rr]);
            }
    }
    const float boA = b_out[pA];
    const float boB = hasB ? b_out[pB] : 0.0f;
#pragma unroll
    for (int rr = 0; rr < 8; ++rr) {
        const size_t orow = (size_t)(row0 + myrow + rr) * P_DIM;
        out[orow + pA] = accA[rr] + boA;
        if (hasB) out[orow + pB] = accB[rr] + boB;
    }
}

extern "C" void kernel_launch(void* const* d_in, const int* in_sizes, int n_in,
                              void* d_out, int out_size, void* d_ws, size_t ws_size,
                              hipStream_t stream) {
    const float* x     = (const float*)d_in[0];
    const float* W_ih  = (const float*)d_in[1];
    const float* W_hh  = (const float*)d_in[2];
    const float* b_ih  = (const float*)d_in[3];
    const float* b_hh  = (const float*)d_in[4];
    const float* W_out = (const float*)d_in[5];
    const float* b_out = (const float*)d_in[6];
    float* out = (float*)d_out;

    const size_t bpack_elems = 8 * 48 * 64 * 8;          // 196608 f16 per matrix
    const size_t wot_elems   = (size_t)H_DIM * P_DIM;    // 24576 fp32
    const size_t ctr_off = bpack_elems * 2 * sizeof(unsigned short) * 2 +
                           wot_elems * sizeof(float);    // 1671168 B (16-aligned)
    const size_t need = ctr_off + sizeof(unsigned int);

    if (ws_size >= need) {
        unsigned short* Bh = (unsigned short*)d_ws;
        unsigned short* Bl = Bh + bpack_elems * 2;
        float* WoT = (float*)(Bl + bpack_elems * 2);
        unsigned int* ctr = (unsigned int*)((char*)d_ws + ctr_off);
        pack_weights<<<G3, H_DIM, 0, stream>>>(W_hh, W_out, Bh, Bl, WoT, ctr);
        gru_mfma<<<B_ROWS / TB, 512, 0, stream>>>(x, W_ih, b_ih, b_hh,
                                                  Bh, Bl, WoT, b_out, out, ctr);
    } else {
        gru_fallback<<<B_ROWS / TB, 256, 0, stream>>>(x, W_ih, W_hh, b_ih, b_hh,
                                                      W_out, b_out, out);
    }
}

// Round 5
// 4742.916 us; speedup vs baseline: 1.1006x; 1.1006x over previous
//
#include <hip/hip_runtime.h>
#include <math.h>

// Problem constants
#define B_ROWS 8192
#define S_LEN  512
#define H_DIM  256
#define G3     768          // 3*H
#define P_DIM  96
#define TB     32           // batch rows per block
#define BPACK  196608       // f16 elems per packed matrix copy (384 tiles x 512)

typedef __attribute__((ext_vector_type(8))) _Float16 half8;  // 8 f16 (4 VGPRs)
typedef __attribute__((ext_vector_type(4))) float floatx4;   // MFMA C/D frag

__device__ __forceinline__ float sigmoid_fast(float v) {
    return 1.0f / (1.0f + __expf(-v));
}
__device__ __forceinline__ float tanh_fast(float v) {
    return 1.0f - 2.0f / (__expf(2.0f * v) + 1.0f);
}
__device__ __forceinline__ unsigned short f32_f16(float f) {
    _Float16 h = (_Float16)f;                 // RTN
    return __builtin_bit_cast(unsigned short, h);
}
// Involutive 6-bit lane rotation: spreads scatter dest-lanes across bank groups.
__device__ __forceinline__ int rot3(int l) { return ((l << 3) | (l >> 3)) & 63; }

// -------- One-time weight pack: W_hh -> per-lane MFMA B-fragments (hi/lo fp16),
// replicated R times (R=4 when workspace allows). Replication de-contends the
// L2: CUs in one XCD split across copies instead of hammering the same lines.
// B[k][n] = W_hh[n][k].  16x16x32 B-frag: lane holds B[n=lane&15][k=quad*8+j].
// Tile index = (k>>5)*48 + (j>>4); lane = (j&15) | (((k>>3)&3)<<4); short = k&7.
// Also WoT[k][p] = W_out[p][k]; also zeroes the phase-sync counter.
__global__ void pack_weights(const float* __restrict__ W_hh,
                             const float* __restrict__ W_out,
                             unsigned short* __restrict__ Bh,
                             unsigned short* __restrict__ Bl,
                             float* __restrict__ WoT,
                             unsigned int* __restrict__ ctr,
                             int R) {
    const int j = blockIdx.x;    // gate col 0..767
    const int k = threadIdx.x;   // h idx   0..255
    const float wv = W_hh[j * H_DIM + k];
    const unsigned short hi = f32_f16(wv);
    const float hf = (float)__builtin_bit_cast(_Float16, hi);
    const unsigned short lo = f32_f16(wv - hf);
    const int idx = (((k >> 5) * 48 + (j >> 4)) * 64 +
                     ((j & 15) | (((k >> 3) & 3) << 4))) * 8 + (k & 7);
    for (int r = 0; r < R; ++r) {
        Bh[(size_t)r * BPACK + idx] = hi;
        Bl[(size_t)r * BPACK + idx] = lo;
    }
    if (j < P_DIM) WoT[k * P_DIM + j] = W_out[j * H_DIM + k];
    if (j == 0 && k == 0) *ctr = 0u;   // d_ws is re-poisoned every launch
}

// LDS layout (132 KiB total):
//   [0,       32768)  A-fragments (fp16), double-buffered:
//                     buf*16384 + chunk(kc*2+mt)*1024 + slot*16 + short*2
//                     (slot = rot3'd fragment-lane index)
//   [32768,   36864)  xtile[2][32][16] fp32
//   [36864,  135168)  W cache: 96 tiles x 1 KiB = kc=6 hi (slots 0..47,
//                     index T=(gh>>1)*16+w*2+(gh&1)) and kc=6 lo (48..95)
#define A_OFF   0
#define X_OFF   32768
#define W_OFF   36864
#define LDS_SZ  135168

__device__ __forceinline__ void mfma2(floatx4& c0, floatx4& c1,
                                      const half8& a0, const half8& a1,
                                      const half8& bh, const half8& bl) {
    c0 = __builtin_amdgcn_mfma_f32_16x16x32_f16(a0, bh, c0, 0, 0, 0);
    c1 = __builtin_amdgcn_mfma_f32_16x16x32_f16(a1, bh, c1, 0, 0, 0);
    c0 = __builtin_amdgcn_mfma_f32_16x16x32_f16(a0, bl, c0, 0, 0, 0);
    c1 = __builtin_amdgcn_mfma_f32_16x16x32_f16(a1, bl, c1, 0, 0, 0);
}

// Issue 12 streamed tile loads for one kc (stay in flight until MFMA use).
__device__ __forceinline__ void gissue(half8 (&BH)[6], half8 (&BL)[6],
                                       const unsigned short* (&pbh)[6],
                                       const unsigned short* (&pbl)[6],
                                       int kc) {
#pragma unroll
    for (int gh = 0; gh < 6; ++gh) {
        BH[gh] = *(const half8*)(pbh[gh] + (size_t)kc * 24576);
        BL[gh] = *(const half8*)(pbl[gh] + (size_t)kc * 24576);
    }
}

__device__ __forceinline__ void ahread(half8 (&AH)[2], const char* Ac,
                                       int kc, int rl) {
#pragma unroll
    for (int mt = 0; mt < 2; ++mt)
        AH[mt] = *(const half8*)(Ac + (kc * 2 + mt) * 1024 + rl * 16);
}

__device__ __forceinline__ void kcmfma(floatx4 (&acc)[3][2][2],
                                       const half8 (&AH)[2],
                                       const half8 (&BH)[6],
                                       const half8 (&BL)[6]) {
#pragma unroll
    for (int gh = 0; gh < 6; ++gh)
        mfma2(acc[gh >> 1][0][gh & 1], acc[gh >> 1][1][gh & 1],
              AH[0], AH[1], BH[gh], BL[gh]);
}

// Main persistent GRU kernel: fp16 single-A / split-W MFMA, software-pipelined
// weight stream (one-kc-ahead register double buffer, one-ahead A-frag reads).
// Weight replication: block uses copy (blockIdx>>3)&(R-1), so the 32 CUs of
// one XCD split 8-per-copy instead of 32 on the same lines (L2 de-contend).
// grid = 256 (1 block/CU, forced by 132 KiB LDS), block = 512 (8 waves).
__global__ __launch_bounds__(512, 2)
void gru_mfma(const float* __restrict__ x,
              const float* __restrict__ W_ih,
              const float* __restrict__ b_ih,
              const float* __restrict__ b_hh,
              const unsigned short* __restrict__ Bh,
              const unsigned short* __restrict__ Bl,
              const float* __restrict__ WoT,   // [256][96]
              const float* __restrict__ b_out,
              float* __restrict__ out,
              unsigned int* __restrict__ ctr,
              int R) {
    __shared__ __align__(16) char smem[LDS_SZ];

    const int tid  = threadIdx.x;
    const int w    = tid >> 6;     // wave 0..7
    const int lane = tid & 63;
    const int q    = lane >> 4;    // quad
    const int c    = lane & 15;
    const int row0 = blockIdx.x * TB;

    // Replica base for this CU (R is 1 or 4; power of 2).
    const size_t rep_off = (size_t)((blockIdx.x >> 3) & (R - 1)) * BPACK;

    // Per-thread gate params; col = 256*g + 32*w + 16*ht + c
    float wih[3][2], bcc[2][2], bihn[2], bhhn[2];
#pragma unroll
    for (int g = 0; g < 3; ++g)
#pragma unroll
        for (int ht = 0; ht < 2; ++ht) {
            const int col = g * H_DIM + w * 32 + ht * 16 + c;
            wih[g][ht] = W_ih[col];
            if (g < 2) {
                bcc[g][ht] = b_ih[col] + b_hh[col];
            } else {
                bihn[ht] = b_ih[col];
                bhhn[ht] = b_hh[col];
            }
        }

    // Streamed-tile base pointers (per wave/lane), gh = g*2 + ht.
    const unsigned short* pbh[6];
    const unsigned short* pbl[6];
#pragma unroll
    for (int gh = 0; gh < 6; ++gh) {
        const size_t toff = rep_off +
            (size_t)((gh >> 1) * 16 + w * 2 + (gh & 1)) * 512 + lane * 8;
        pbh[gh] = Bh + toff;
        pbl[gh] = Bl + toff;
    }

    // Register-resident weight tiles: kc=7 hi+lo.  (48 VGPRs)
    half8 r7h[6], r7l[6];
#pragma unroll
    for (int gh = 0; gh < 6; ++gh) {
        r7h[gh] = *(const half8*)(pbh[gh] + 7 * 24576);
        r7l[gh] = *(const half8*)(pbl[gh] + 7 * 24576);
    }

    // LDS weight cache staging: 96 tiles = kc=6 hi (0..47) + kc=6 lo (48..95).
    for (int i = tid; i < 96 * 64; i += 512) {
        const int slot = i >> 6, l16 = i & 63;
        const unsigned short* src = (slot < 48)
            ? (Bh + rep_off + (size_t)(288 + slot) * 512 + l16 * 8)
            : (Bl + rep_off + (size_t)(288 + slot - 48) * 512 + l16 * 8);
        *(uint4*)(smem + W_OFF + slot * 1024 + l16 * 16) = *(const uint4*)src;
    }

    // Zero both A-frag buffers (h0 = 0) and stage x for t=0..15.
    for (int i = tid; i < 8192; i += 512) ((int*)(smem + A_OFF))[i] = 0;
    float* xt = (float*)(smem + X_OFF);
    {
        const int r = tid >> 4, t2 = tid & 15;
        xt[r * 16 + t2] = x[(size_t)(row0 + r) * S_LEN + t2];
    }
    __syncthreads();

    // h_old in C-frag layout: element (mt,ht,reg) = h[4q+reg+16mt][32w+16ht+c]
    float h_own[2][2][4];
#pragma unroll
    for (int mt = 0; mt < 2; ++mt)
#pragma unroll
        for (int ht = 0; ht < 2; ++ht)
#pragma unroll
            for (int r = 0; r < 4; ++r) h_own[mt][ht][r] = 0.0f;

    const int rl = rot3(lane);

    // Pipeline buffers (static names only — rule: no runtime indexing).
    half8 b0h[6], b0l[6], b1h[6], b1l[6];
    half8 ahA[2], ahB[2];

    // Prologue: kc=0 of step 0 in flight before the loop.
    gissue(b0h, b0l, pbh, pbl, 0);

#pragma unroll 1
    for (int t = 0; t < S_LEN; ++t) {
        // Defeat LICM of the (t-invariant) streamed loads: make the stream
        // pointers opaque each iteration so loads stay inside the loop.
#pragma unroll
        for (int gh = 0; gh < 6; ++gh)
            asm volatile("" : "+v"(pbh[gh]), "+v"(pbl[gh]));

        const int cur = t & 1, nxt = cur ^ 1;
        const char* Ac = smem + A_OFF + cur * 16384;

        ahread(ahA, Ac, 0, rl);            // A-frags for kc=0
        gissue(b1h, b1l, pbh, pbl, 1);     // kc=1 stream in flight

        // x for my 8 rows (LDS broadcast)
        float xr[2][4];
#pragma unroll
        for (int mt = 0; mt < 2; ++mt)
#pragma unroll
            for (int r = 0; r < 4; ++r)
                xr[mt][r] = xt[(((t >> 4) & 1) * 32 + q * 4 + r + 16 * mt) * 16 + (t & 15)];

        // C frags [gate][mt][ht]; fold x-side pre-activation + bias into init.
        floatx4 acc[3][2][2];
#pragma unroll
        for (int mt = 0; mt < 2; ++mt)
#pragma unroll
            for (int ht = 0; ht < 2; ++ht)
#pragma unroll
                for (int r = 0; r < 4; ++r) {
                    acc[0][mt][ht][r] = fmaf(xr[mt][r], wih[0][ht], bcc[0][ht]);
                    acc[1][mt][ht][r] = fmaf(xr[mt][r], wih[1][ht], bcc[1][ht]);
                    acc[2][mt][ht][r] = bhhn[ht];
                }

        // ---- Pipelined kc ladder: consume kc, stream kc+1, read A(kc+1) ----
        ahread(ahB, Ac, 1, rl);
        kcmfma(acc, ahA, b0h, b0l);                       // kc0
        gissue(b0h, b0l, pbh, pbl, 2);
        ahread(ahA, Ac, 2, rl);
        kcmfma(acc, ahB, b1h, b1l);                       // kc1
        gissue(b1h, b1l, pbh, pbl, 3);
        ahread(ahB, Ac, 3, rl);
        kcmfma(acc, ahA, b0h, b0l);                       // kc2
        gissue(b0h, b0l, pbh, pbl, 4);
        ahread(ahA, Ac, 4, rl);
        kcmfma(acc, ahB, b1h, b1l);                       // kc3
        gissue(b1h, b1l, pbh, pbl, 5);
        ahread(ahB, Ac, 5, rl);
        kcmfma(acc, ahA, b0h, b0l);                       // kc4
        ahread(ahA, Ac, 6, rl);
        kcmfma(acc, ahB, b1h, b1l);                       // kc5

        // ---- kc6: hi+lo from the LDS cache ----
        {
            half8 w6h[6], w6l[6];
#pragma unroll
            for (int gh = 0; gh < 6; ++gh) {
                const int T = (gh >> 1) * 16 + w * 2 + (gh & 1);
                w6h[gh] = *(const half8*)(smem + W_OFF + T * 1024 + lane * 16);
                w6l[gh] = *(const half8*)(smem + W_OFF + (48 + T) * 1024 + lane * 16);
            }
            ahread(ahB, Ac, 7, rl);
            kcmfma(acc, ahA, w6h, w6l);                   // kc6
        }

        // Prefetch next step's kc0 while kc7 + gates + barrier run
        // (weights are t-invariant: same addresses every step, no guard).
        gissue(b0h, b0l, pbh, pbl, 0);
        kcmfma(acc, ahB, r7h, r7l);                       // kc7

        // Gates + h update (in-register); scatter next A-frags (rot3-swizzled).
        char* Anx = smem + A_OFF + nxt * 16384;
#pragma unroll
        for (int mt = 0; mt < 2; ++mt) {
            char* ch = Anx + (w * 2 + mt) * 1024;         // chunk kc=w
#pragma unroll
            for (int ht = 0; ht < 2; ++ht)
#pragma unroll
                for (int r = 0; r < 4; ++r) {
                    const float rr  = sigmoid_fast(acc[0][mt][ht][r]);
                    const float zz  = sigmoid_fast(acc[1][mt][ht][r]);
                    const float inn = fmaf(xr[mt][r], wih[2][ht], bihn[ht]);
                    const float nn  = tanh_fast(fmaf(rr, acc[2][mt][ht][r], inn));
                    const float hv  = (1.0f - zz) * nn + zz * h_own[mt][ht][r];
                    h_own[mt][ht][r] = hv;
                    const int d    = (q * 4 + r) | ((2 * ht + (c >> 3)) << 4);
                    const int off  = rot3(d) * 16 + (c & 7) * 2;
                    *(unsigned short*)(ch + off) = f32_f16(hv);
                }
        }

        // Re-stage x for the next 16 steps (into the idle x buffer).
        const bool tick = ((t & 15) == 15) && (t != S_LEN - 1);
        if (tick) {
            const int r = tid >> 4, t2 = tid & 15;
            xt[((((t + 1) >> 4) & 1) * 32 + r) * 16 + t2] =
                x[(size_t)(row0 + r) * S_LEN + (t + 1) + t2];
        }
        __syncthreads();   // single barrier: next A-frags + x tile visible

        // Phase-alignment heartbeat every 16 steps: keeps all 256 blocks'
        // weight streams in phase so the per-XCD L2 working set stays hot.
        // Pure timing hint — bounded spin, no data dependency, no fences.
        if (tick) {
            if (tid == 0) {
                const unsigned int tgt = 256u * (unsigned)((t >> 4) + 1);
                atomicAdd(ctr, 1u);
                for (int spin = 0; spin < (1 << 17); ++spin) {
                    if (__hip_atomic_load(ctr, __ATOMIC_RELAXED,
                                          __HIP_MEMORY_SCOPE_AGENT) >= tgt) break;
                    __builtin_amdgcn_s_sleep(4);
                }
            }
            __syncthreads();
        }
    }

    // -------- Epilogue: dump final h (fp32, from registers) and project.
    float* hfin = (float*)(smem);   // reuse A region: [32][256] = 32 KiB
#pragma unroll
    for (int mt = 0; mt < 2; ++mt)
#pragma unroll
        for (int ht = 0; ht < 2; ++ht)
#pragma unroll
            for (int r = 0; r < 4; ++r) {
                const int m = q * 4 + r + 16 * mt;
                const int k = w * 32 + ht * 16 + c;
                hfin[m * H_DIM + k] = h_own[mt][ht][r];
            }
    __syncthreads();

    if (tid < 256) {
        const int cid   = tid & 63;
        const int rid   = tid >> 6;
        const int myrow = rid * 8;
        const int pA    = cid;
        const int pB    = 64 + cid;
        const bool hasB = (cid < 32);
        float accA[8], accB[8];
#pragma unroll
        for (int rr = 0; rr < 8; ++rr) { accA[rr] = 0.0f; accB[rr] = 0.0f; }

        for (int k = 0; k < H_DIM; k += 4) {
            float4 hv[8];
#pragma unroll
            for (int rr = 0; rr < 8; ++rr)
                hv[rr] = *(const float4*)&hfin[(myrow + rr) * H_DIM + k];
            float wA[4], wB[4];
#pragma unroll
            for (int kk = 0; kk < 4; ++kk) {
                wA[kk] = WoT[(size_t)(k + kk) * P_DIM + pA];
                wB[kk] = hasB ? WoT[(size_t)(k + kk) * P_DIM + pB] : 0.0f;
            }
#pragma unroll
            for (int kk = 0; kk < 4; ++kk)
#pragma unroll
                for (int rr = 0; rr < 8; ++rr) {
                    const float hvv = (&hv[rr].x)[kk];
                    accA[rr] = fmaf(hvv, wA[kk], accA[rr]);
                    accB[rr] = fmaf(hvv, wB[kk], accB[rr]);
                }
        }
        const float boA = b_out[pA];
        const float boB = hasB ? b_out[pB] : 0.0f;
#pragma unroll
        for (int rr = 0; rr < 8; ++rr) {
            const size_t orow = (size_t)(row0 + myrow + rr) * P_DIM;
            out[orow + pA] = accA[rr] + boA;
            if (hasB) out[orow + pB] = accB[rr] + boB;
        }
    }
}

// -------- fp32 fallback — used only if ws_size is too small.
__global__ __launch_bounds__(256, 1)
void gru_fallback(const float* __restrict__ x,
                  const float* __restrict__ W_ih,
                  const float* __restrict__ Whh,
                  const float* __restrict__ b_ih,
                  const float* __restrict__ b_hh,
                  const float* __restrict__ Wout,
                  const float* __restrict__ b_out,
                  float* __restrict__ out) {
    __shared__ float hbuf[2][TB][H_DIM];

    const int tid   = threadIdx.x;
    const int cid   = tid & 63;
    const int rid   = tid >> 6;
    const int row0  = blockIdx.x * TB;
    const int myrow = rid * 8;
    const int c0    = cid * 4;

    float wih[3][4], bc[2][4], bihn[4], bhhn[4];
#pragma unroll
    for (int cc = 0; cc < 4; ++cc) {
        const int j = c0 + cc;
        wih[0][cc] = W_ih[j];
        wih[1][cc] = W_ih[H_DIM + j];
        wih[2][cc] = W_ih[2 * H_DIM + j];
        bc[0][cc]  = b_ih[j] + b_hh[j];
        bc[1][cc]  = b_ih[H_DIM + j] + b_hh[H_DIM + j];
        bihn[cc]   = b_ih[2 * H_DIM + j];
        bhhn[cc]   = b_hh[2 * H_DIM + j];
    }
    for (int i = tid; i < TB * H_DIM; i += 256) (&hbuf[0][0][0])[i] = 0.0f;
    float h_own[8][4];
#pragma unroll
    for (int rr = 0; rr < 8; ++rr)
#pragma unroll
        for (int cc = 0; cc < 4; ++cc) h_own[rr][cc] = 0.0f;
    __syncthreads();

    int p = 0;
    for (int t = 0; t < S_LEN; ++t) {
        float xv[8];
#pragma unroll
        for (int rr = 0; rr < 8; ++rr)
            xv[rr] = x[(size_t)(row0 + myrow + rr) * S_LEN + t];

        float acc[3][8][4];
#pragma unroll
        for (int rr = 0; rr < 8; ++rr)
#pragma unroll
            for (int cc = 0; cc < 4; ++cc) {
                acc[0][rr][cc] = fmaf(xv[rr], wih[0][cc], bc[0][cc]);
                acc[1][rr][cc] = fmaf(xv[rr], wih[1][cc], bc[1][cc]);
                acc[2][rr][cc] = bhhn[cc];
            }
        const float* hb = &hbuf[p][0][0];
        for (int k = 0; k < H_DIM; k += 4) {
            float4 hv[8];
#pragma unroll
            for (int rr = 0; rr < 8; ++rr)
                hv[rr] = *(const float4*)(hb + (myrow + rr) * H_DIM + k);
#pragma unroll
            for (int g = 0; g < 3; ++g)
#pragma unroll
                for (int kk = 0; kk < 4; ++kk) {
                    float wrow[4];
#pragma unroll
                    for (int cc = 0; cc < 4; ++cc)
                        wrow[cc] = Whh[(size_t)(g * H_DIM + c0 + cc) * H_DIM + k + kk];
#pragma unroll
                    for (int rr = 0; rr < 8; ++rr) {
                        const float hvv = (&hv[rr].x)[kk];
#pragma unroll
                        for (int cc = 0; cc < 4; ++cc)
                            acc[g][rr][cc] = fmaf(hvv, wrow[cc], acc[g][rr][cc]);
                    }
                }
        }
#pragma unroll
        for (int rr = 0; rr < 8; ++rr) {
            float4 hnew;
#pragma unroll
            for (int cc = 0; cc < 4; ++cc) {
                const float r_  = sigmoid_fast(acc[0][rr][cc]);
                const float z_  = sigmoid_fast(acc[1][rr][cc]);
                const float i_n = fmaf(xv[rr], wih[2][cc], bihn[cc]);
                const float n_  = tanh_fast(fmaf(r_, acc[2][rr][cc], i_n));
                const float hv2 = (1.0f - z_) * n_ + z_ * h_own[rr][cc];
                h_own[rr][cc] = hv2;
                (&hnew.x)[cc] = hv2;
            }
            *(float4*)&hbuf[1 - p][myrow + rr][c0] = hnew;
        }
        __syncthreads();
        p ^= 1;
    }

    const int  pA   = cid;
    const int  pB   = 64 + cid;
    const bool hasB = (cid < 32);
    float accA[8], accB[8];
#pragma unroll
    for (int rr = 0; rr < 8; ++rr) { accA[rr] = 0.0f; accB[rr] = 0.0f; }
    for (int k = 0; k < H_DIM; k += 4) {
        float4 hv[8];
#pragma unroll
        for (int rr = 0; rr < 8; ++rr)
            hv[rr] = *(const float4*)&hbuf[p][myrow + rr][k];
        float wA[4], wB[4];
#pragma unroll
        for (int kk = 0; kk < 4; ++kk) {
            wA[kk] = Wout[(size_t)pA * H_DIM + k + kk];
            wB[kk] = hasB ? Wout[(size_t)pB * H_DIM + k + kk] : 0.0f;
        }
#pragma unroll
        for (int kk = 0; kk < 4; ++kk)
#pragma unroll
            for (int rr = 0; rr < 8; ++rr) {
                const float hvv = (&hv[rr].x)[kk];
                accA[rr] = fmaf(hvv, wA[kk], accA[rr]);
                accB[rr] = fmaf(hvv, wB[kk], accB[rr]);
            }
    }
    const float boA = b_out[pA];
    const float boB = hasB ? b_out[pB] : 0.0f;
#pragma unroll
    for (int rr = 0; rr < 8; ++rr) {
        const size_t orow = (size_t)(row0 + myrow + rr) * P_DIM;
        out[orow + pA] = accA[rr] + boA;
        if (hasB) out[orow + pB] = accB[rr] + boB;
    }
}

extern "C" void kernel_launch(void* const* d_in, const int* in_sizes, int n_in,
                              void* d_out, int out_size, void* d_ws, size_t ws_size,
                              hipStream_t stream) {
    const float* x     = (const float*)d_in[0];
    const float* W_ih  = (const float*)d_in[1];
    const float* W_hh  = (const float*)d_in[2];
    const float* b_ih  = (const float*)d_in[3];
    const float* b_hh  = (const float*)d_in[4];
    const float* W_out = (const float*)d_in[5];
    const float* b_out = (const float*)d_in[6];
    float* out = (float*)d_out;

    const size_t wot_bytes = (size_t)H_DIM * P_DIM * sizeof(float);  // 98304

    // Pick replication factor: 4 if the workspace holds it, else 1.
    auto need_for = [&](int R) {
        return (size_t)R * BPACK * sizeof(unsigned short) * 2   // Bh + Bl
               + wot_bytes + sizeof(unsigned int);
    };
    int R = (ws_size >= need_for(4)) ? 4 : 1;

    if (ws_size >= need_for(R)) {
        unsigned short* Bh = (unsigned short*)d_ws;
        unsigned short* Bl = Bh + (size_t)R * BPACK;
        float* WoT = (float*)(Bl + (size_t)R * BPACK);
        unsigned int* ctr = (unsigned int*)((char*)WoT + wot_bytes);
        pack_weights<<<G3, H_DIM, 0, stream>>>(W_hh, W_out, Bh, Bl, WoT, ctr, R);
        gru_mfma<<<B_ROWS / TB, 512, 0, stream>>>(x, W_ih, b_ih, b_hh,
                                                  Bh, Bl, WoT, b_out, out, ctr, R);
    } else {
        gru_fallback<<<B_ROWS / TB, 256, 0, stream>>>(x, W_ih, W_hh, b_ih, b_hh,
                                                      W_out, b_out, out);
    }
}

// Round 6
// 4740.315 us; speedup vs baseline: 1.1012x; 1.0005x over previous
//
#include <hip/hip_runtime.h>
#include <math.h>

// Problem constants
#define B_ROWS 8192
#define S_LEN  512
#define H_DIM  256
#define G3     768          // 3*H
#define P_DIM  96
#define TB     32           // batch rows per block

typedef __attribute__((ext_vector_type(8))) _Float16 half8;  // 8 f16 (4 VGPRs)
typedef __attribute__((ext_vector_type(4))) float floatx4;   // MFMA C/D frag

__device__ __forceinline__ float sigmoid_fast(float v) {
    return 1.0f / (1.0f + __expf(-v));
}
__device__ __forceinline__ float tanh_fast(float v) {
    return 1.0f - 2.0f / (__expf(2.0f * v) + 1.0f);
}
__device__ __forceinline__ unsigned short f32_f16(float f) {
    _Float16 h = (_Float16)f;                 // RTN
    return __builtin_bit_cast(unsigned short, h);
}
// Involutive 6-bit lane rotation: spreads scatter dest-lanes across bank groups.
__device__ __forceinline__ int rot3(int l) { return ((l << 3) | (l >> 3)) & 63; }

// -------- One-time weight pack: W_hh -> per-lane MFMA B-fragments (hi/lo fp16).
// h in (-1,1) is sent as SINGLE fp16; W is split hi+lo fp16 (~2^-22 capture).
// B[k][n] = W_hh[n][k].  16x16x32 B-frag: lane holds B[n=lane&15][k=quad*8+j].
// Tile index = (k>>5)*48 + (j>>4); lane = (j&15) | (((k>>3)&3)<<4); short = k&7.
// Also WoT[k][p] = W_out[p][k]; also zeroes the phase-sync counter.
__global__ void pack_weights(const float* __restrict__ W_hh,
                             const float* __restrict__ W_out,
                             unsigned short* __restrict__ Bh,
                             unsigned short* __restrict__ Bl,
                             float* __restrict__ WoT,
                             unsigned int* __restrict__ ctr) {
    const int j = blockIdx.x;    // gate col 0..767
    const int k = threadIdx.x;   // h idx   0..255
    const float wv = W_hh[j * H_DIM + k];
    const unsigned short hi = f32_f16(wv);
    const float hf = (float)__builtin_bit_cast(_Float16, hi);
    const unsigned short lo = f32_f16(wv - hf);
    const int idx = (((k >> 5) * 48 + (j >> 4)) * 64 +
                     ((j & 15) | (((k >> 3) & 3) << 4))) * 8 + (k & 7);
    Bh[idx] = hi;
    Bl[idx] = lo;
    if (j < P_DIM) WoT[k * P_DIM + j] = W_out[j * H_DIM + k];
    if (j == 0 && k == 0) *ctr = 0u;   // d_ws is re-poisoned every launch
}

// LDS layout (132 KiB total):
//   [0,       32768)  A-fragments (fp16), double-buffered:
//                     buf*16384 + chunk(kc*2+mt)*1024 + slot*16 + short*2
//                     (slot = rot3'd fragment-lane index)
//   [32768,   36864)  xtile[2][32][16] fp32
//   [36864,  135168)  W cache: 96 tiles x 1 KiB = kc=6 hi (slots 0..47,
//                     index T=(gh>>1)*16+w*2+(gh&1)) and kc=6 lo (48..95)
#define A_OFF   0
#define X_OFF   32768
#define W_OFF   36864
#define LDS_SZ  135168

__device__ __forceinline__ void mfma2(floatx4& c0, floatx4& c1,
                                      const half8& a0, const half8& a1,
                                      const half8& bh, const half8& bl) {
    c0 = __builtin_amdgcn_mfma_f32_16x16x32_f16(a0, bh, c0, 0, 0, 0);
    c1 = __builtin_amdgcn_mfma_f32_16x16x32_f16(a1, bh, c1, 0, 0, 0);
    c0 = __builtin_amdgcn_mfma_f32_16x16x32_f16(a0, bl, c0, 0, 0, 0);
    c1 = __builtin_amdgcn_mfma_f32_16x16x32_f16(a1, bl, c1, 0, 0, 0);
}

// Issue 12 streamed tile loads for one kc (stay in flight until MFMA use).
__device__ __forceinline__ void gissue(half8 (&BH)[6], half8 (&BL)[6],
                                       const unsigned short* (&pbh)[6],
                                       const unsigned short* (&pbl)[6],
                                       int kc) {
#pragma unroll
    for (int gh = 0; gh < 6; ++gh) {
        BH[gh] = *(const half8*)(pbh[gh] + (size_t)kc * 24576);
        BL[gh] = *(const half8*)(pbl[gh] + (size_t)kc * 24576);
    }
}

__device__ __forceinline__ void ahread(half8 (&AH)[2], const char* Ac,
                                       int kc, int rl) {
#pragma unroll
    for (int mt = 0; mt < 2; ++mt)
        AH[mt] = *(const half8*)(Ac + (kc * 2 + mt) * 1024 + rl * 16);
}

__device__ __forceinline__ void kcmfma(floatx4 (&acc)[3][2][2],
                                       const half8 (&AH)[2],
                                       const half8 (&BH)[6],
                                       const half8 (&BL)[6]) {
#pragma unroll
    for (int gh = 0; gh < 6; ++gh)
        mfma2(acc[gh >> 1][0][gh & 1], acc[gh >> 1][1][gh & 1],
              AH[0], AH[1], BH[gh], BL[gh]);
}

// Main persistent GRU kernel: fp16 single-A / split-W MFMA, software-pipelined
// weight stream (one-kc-ahead register double buffer, one-ahead A-frag reads).
// amdgpu_waves_per_eu(2,2): LDS already caps the CU at 1 block (= 2 waves/EU),
// so pin the allocator there -> full 256-VGPR budget, keeping the pipeline
// buffers + kc7 tiles genuinely register-resident (VGPR_Count was 128: the
// allocator chased unreachable 4-wave occupancy and rematerialized instead).
// grid = 256 (1 block/CU, forced by 132 KiB LDS), block = 512 (8 waves).
__global__ __launch_bounds__(512)
__attribute__((amdgpu_waves_per_eu(2, 2)))
void gru_mfma(const float* __restrict__ x,
              const float* __restrict__ W_ih,
              const float* __restrict__ b_ih,
              const float* __restrict__ b_hh,
              const unsigned short* __restrict__ Bh,
              const unsigned short* __restrict__ Bl,
              const float* __restrict__ WoT,   // [256][96]
              const float* __restrict__ b_out,
              float* __restrict__ out,
              unsigned int* __restrict__ ctr) {
    __shared__ __align__(16) char smem[LDS_SZ];

    const int tid  = threadIdx.x;
    const int w    = tid >> 6;     // wave 0..7
    const int lane = tid & 63;
    const int q    = lane >> 4;    // quad
    const int c    = lane & 15;
    const int row0 = blockIdx.x * TB;

    // Per-thread gate params; col = 256*g + 32*w + 16*ht + c
    float wih[3][2], bcc[2][2], bihn[2], bhhn[2];
#pragma unroll
    for (int g = 0; g < 3; ++g)
#pragma unroll
        for (int ht = 0; ht < 2; ++ht) {
            const int col = g * H_DIM + w * 32 + ht * 16 + c;
            wih[g][ht] = W_ih[col];
            if (g < 2) {
                bcc[g][ht] = b_ih[col] + b_hh[col];
            } else {
                bihn[ht] = b_ih[col];
                bhhn[ht] = b_hh[col];
            }
        }

    // Streamed-tile base pointers (per wave/lane), gh = g*2 + ht.
    const unsigned short* pbh[6];
    const unsigned short* pbl[6];
#pragma unroll
    for (int gh = 0; gh < 6; ++gh) {
        const size_t toff = (size_t)((gh >> 1) * 16 + w * 2 + (gh & 1)) * 512 + lane * 8;
        pbh[gh] = Bh + toff;
        pbl[gh] = Bl + toff;
    }

    // Register-resident weight tiles: kc=7 hi+lo.  (48 VGPRs)
    half8 r7h[6], r7l[6];
#pragma unroll
    for (int gh = 0; gh < 6; ++gh) {
        r7h[gh] = *(const half8*)(pbh[gh] + 7 * 24576);
        r7l[gh] = *(const half8*)(pbl[gh] + 7 * 24576);
    }

    // LDS weight cache staging: 96 tiles = kc=6 hi (0..47) + kc=6 lo (48..95).
    for (int i = tid; i < 96 * 64; i += 512) {
        const int slot = i >> 6, l16 = i & 63;
        const unsigned short* src = (slot < 48)
            ? (Bh + (size_t)(288 + slot) * 512 + l16 * 8)
            : (Bl + (size_t)(288 + slot - 48) * 512 + l16 * 8);
        *(uint4*)(smem + W_OFF + slot * 1024 + l16 * 16) = *(const uint4*)src;
    }

    // Zero both A-frag buffers (h0 = 0) and stage x for t=0..15.
    for (int i = tid; i < 8192; i += 512) ((int*)(smem + A_OFF))[i] = 0;
    float* xt = (float*)(smem + X_OFF);
    {
        const int r = tid >> 4, t2 = tid & 15;
        xt[r * 16 + t2] = x[(size_t)(row0 + r) * S_LEN + t2];
    }
    __syncthreads();

    // h_old in C-frag layout: element (mt,ht,reg) = h[4q+reg+16mt][32w+16ht+c]
    float h_own[2][2][4];
#pragma unroll
    for (int mt = 0; mt < 2; ++mt)
#pragma unroll
        for (int ht = 0; ht < 2; ++ht)
#pragma unroll
            for (int r = 0; r < 4; ++r) h_own[mt][ht][r] = 0.0f;

    const int rl = rot3(lane);

    // Loop-invariant precompute: scatter byte offsets (within a chunk) for
    // each (ht,r), x-tile row offsets for each (mt,r), kc6 LDS tile bases.
    int soff[2][4];                 // [ht][r] -> rot3(d)*16 + (c&7)*2
#pragma unroll
    for (int ht = 0; ht < 2; ++ht)
#pragma unroll
        for (int r = 0; r < 4; ++r) {
            const int d = (q * 4 + r) | ((2 * ht + (c >> 3)) << 4);
            soff[ht][r] = rot3(d) * 16 + (c & 7) * 2;
        }
    int xbase[2][4];                // [mt][r] -> (q*4+r+16mt)*16
#pragma unroll
    for (int mt = 0; mt < 2; ++mt)
#pragma unroll
        for (int r = 0; r < 4; ++r)
            xbase[mt][r] = (q * 4 + r + 16 * mt) * 16;
    const char* w6base[6];          // kc6 hi tile; lo = +48 KiB
#pragma unroll
    for (int gh = 0; gh < 6; ++gh) {
        const int T = (gh >> 1) * 16 + w * 2 + (gh & 1);
        w6base[gh] = smem + W_OFF + T * 1024 + lane * 16;
    }

    // Pipeline buffers (static names only — rule: no runtime indexing).
    half8 b0h[6], b0l[6], b1h[6], b1l[6];
    half8 ahA[2], ahB[2];

    // Prologue: kc=0 of step 0 in flight before the loop.
    gissue(b0h, b0l, pbh, pbl, 0);

#pragma unroll 1
    for (int t = 0; t < S_LEN; ++t) {
        // Defeat LICM of the (t-invariant) streamed loads: make the stream
        // pointers opaque each iteration so loads stay inside the loop.
#pragma unroll
        for (int gh = 0; gh < 6; ++gh)
            asm volatile("" : "+v"(pbh[gh]), "+v"(pbl[gh]));

        const int cur = t & 1, nxt = cur ^ 1;
        const char* Ac = smem + A_OFF + cur * 16384;

        ahread(ahA, Ac, 0, rl);            // A-frags for kc=0
        gissue(b1h, b1l, pbh, pbl, 1);     // kc=1 stream in flight

        // x for my 8 rows (LDS broadcast); xidx is wave-uniform per step.
        const int xidx = ((t >> 4) & 1) * 512 + (t & 15);
        float xr[2][4];
#pragma unroll
        for (int mt = 0; mt < 2; ++mt)
#pragma unroll
            for (int r = 0; r < 4; ++r)
                xr[mt][r] = xt[xbase[mt][r] + xidx];

        // C frags [gate][mt][ht]; fold x-side pre-activation + bias into init.
        floatx4 acc[3][2][2];
#pragma unroll
        for (int mt = 0; mt < 2; ++mt)
#pragma unroll
            for (int ht = 0; ht < 2; ++ht)
#pragma unroll
                for (int r = 0; r < 4; ++r) {
                    acc[0][mt][ht][r] = fmaf(xr[mt][r], wih[0][ht], bcc[0][ht]);
                    acc[1][mt][ht][r] = fmaf(xr[mt][r], wih[1][ht], bcc[1][ht]);
                    acc[2][mt][ht][r] = bhhn[ht];
                }

        // ---- Pipelined kc ladder: consume kc, stream kc+1, read A(kc+1) ----
        ahread(ahB, Ac, 1, rl);
        kcmfma(acc, ahA, b0h, b0l);                       // kc0
        gissue(b0h, b0l, pbh, pbl, 2);
        ahread(ahA, Ac, 2, rl);
        kcmfma(acc, ahB, b1h, b1l);                       // kc1
        gissue(b1h, b1l, pbh, pbl, 3);
        ahread(ahB, Ac, 3, rl);
        kcmfma(acc, ahA, b0h, b0l);                       // kc2
        gissue(b0h, b0l, pbh, pbl, 4);
        ahread(ahA, Ac, 4, rl);
        kcmfma(acc, ahB, b1h, b1l);                       // kc3
        gissue(b1h, b1l, pbh, pbl, 5);
        ahread(ahB, Ac, 5, rl);
        kcmfma(acc, ahA, b0h, b0l);                       // kc4
        ahread(ahA, Ac, 6, rl);
        kcmfma(acc, ahB, b1h, b1l);                       // kc5

        // ---- kc6: hi+lo from the LDS cache ----
        {
            half8 w6h[6], w6l[6];
#pragma unroll
            for (int gh = 0; gh < 6; ++gh) {
                w6h[gh] = *(const half8*)(w6base[gh]);
                w6l[gh] = *(const half8*)(w6base[gh] + 48 * 1024);
            }
            ahread(ahB, Ac, 7, rl);
            kcmfma(acc, ahA, w6h, w6l);                   // kc6
        }

        // Prefetch next step's kc0 while kc7 + gates + barrier run
        // (weights are t-invariant: same addresses every step, no guard).
        gissue(b0h, b0l, pbh, pbl, 0);
        kcmfma(acc, ahB, r7h, r7l);                       // kc7

        // Gates + h update (in-register); scatter next A-frags (rot3-swizzled).
        char* Anx = smem + A_OFF + nxt * 16384;
#pragma unroll
        for (int mt = 0; mt < 2; ++mt) {
            char* ch = Anx + (w * 2 + mt) * 1024;         // chunk kc=w
#pragma unroll
            for (int ht = 0; ht < 2; ++ht)
#pragma unroll
                for (int r = 0; r < 4; ++r) {
                    const float rr  = sigmoid_fast(acc[0][mt][ht][r]);
                    const float zz  = sigmoid_fast(acc[1][mt][ht][r]);
                    const float inn = fmaf(xr[mt][r], wih[2][ht], bihn[ht]);
                    const float nn  = tanh_fast(fmaf(rr, acc[2][mt][ht][r], inn));
                    const float hv  = (1.0f - zz) * nn + zz * h_own[mt][ht][r];
                    h_own[mt][ht][r] = hv;
                    *(unsigned short*)(ch + soff[ht][r]) = f32_f16(hv);
                }
        }

        // Re-stage x for the next 16 steps (into the idle x buffer).
        const bool tick = ((t & 15) == 15) && (t != S_LEN - 1);
        if (tick) {
            const int r = tid >> 4, t2 = tid & 15;
            xt[((((t + 1) >> 4) & 1) * 32 + r) * 16 + t2] =
                x[(size_t)(row0 + r) * S_LEN + (t + 1) + t2];
        }
        __syncthreads();   // single barrier: next A-frags + x tile visible

        // Phase-alignment heartbeat every 16 steps: keeps all 256 blocks'
        // weight streams in phase so the per-XCD L2 working set stays hot.
        // Pure timing hint — bounded spin, no data dependency, no fences.
        if (tick) {
            if (tid == 0) {
                const unsigned int tgt = 256u * (unsigned)((t >> 4) + 1);
                atomicAdd(ctr, 1u);
                for (int spin = 0; spin < (1 << 17); ++spin) {
                    if (__hip_atomic_load(ctr, __ATOMIC_RELAXED,
                                          __HIP_MEMORY_SCOPE_AGENT) >= tgt) break;
                    __builtin_amdgcn_s_sleep(4);
                }
            }
            __syncthreads();
        }
    }

    // -------- Epilogue: dump final h (fp32, from registers) and project.
    float* hfin = (float*)(smem);   // reuse A region: [32][256] = 32 KiB
#pragma unroll
    for (int mt = 0; mt < 2; ++mt)
#pragma unroll
        for (int ht = 0; ht < 2; ++ht)
#pragma unroll
            for (int r = 0; r < 4; ++r) {
                const int m = q * 4 + r + 16 * mt;
                const int k = w * 32 + ht * 16 + c;
                hfin[m * H_DIM + k] = h_own[mt][ht][r];
            }
    __syncthreads();

    if (tid < 256) {
        const int cid   = tid & 63;
        const int rid   = tid >> 6;
        const int myrow = rid * 8;
        const int pA    = cid;
        const int pB    = 64 + cid;
        const bool hasB = (cid < 32);
        float accA[8], accB[8];
#pragma unroll
        for (int rr = 0; rr < 8; ++rr) { accA[rr] = 0.0f; accB[rr] = 0.0f; }

        for (int k = 0; k < H_DIM; k += 4) {
            float4 hv[8];
#pragma unroll
            for (int rr = 0; rr < 8; ++rr)
                hv[rr] = *(const float4*)&hfin[(myrow + rr) * H_DIM + k];
            float wA[4], wB[4];
#pragma unroll
            for (int kk = 0; kk < 4; ++kk) {
                wA[kk] = WoT[(size_t)(k + kk) * P_DIM + pA];
                wB[kk] = hasB ? WoT[(size_t)(k + kk) * P_DIM + pB] : 0.0f;
            }
#pragma unroll
            for (int kk = 0; kk < 4; ++kk)
#pragma unroll
                for (int rr = 0; rr < 8; ++rr) {
                    const float hvv = (&hv[rr].x)[kk];
                    accA[rr] = fmaf(hvv, wA[kk], accA[rr]);
                    accB[rr] = fmaf(hvv, wB[kk], accB[rr]);
                }
        }
        const float boA = b_out[pA];
        const float boB = hasB ? b_out[pB] : 0.0f;
#pragma unroll
        for (int rr = 0; rr < 8; ++rr) {
            const size_t orow = (size_t)(row0 + myrow + rr) * P_DIM;
            out[orow + pA] = accA[rr] + boA;
            if (hasB) out[orow + pB] = accB[rr] + boB;
        }
    }
}

// -------- fp32 fallback — used only if ws_size is too small.
__global__ __launch_bounds__(256, 1)
void gru_fallback(const float* __restrict__ x,
                  const float* __restrict__ W_ih,
                  const float* __restrict__ Whh,
                  const float* __restrict__ b_ih,
                  const float* __restrict__ b_hh,
                  const float* __restrict__ Wout,
                  const float* __restrict__ b_out,
                  float* __restrict__ out) {
    __shared__ float hbuf[2][TB][H_DIM];

    const int tid   = threadIdx.x;
    const int cid   = tid & 63;
    const int rid   = tid >> 6;
    const int row0  = blockIdx.x * TB;
    const int myrow = rid * 8;
    const int c0    = cid * 4;

    float wih[3][4], bc[2][4], bihn[4], bhhn[4];
#pragma unroll
    for (int cc = 0; cc < 4; ++cc) {
        const int j = c0 + cc;
        wih[0][cc] = W_ih[j];
        wih[1][cc] = W_ih[H_DIM + j];
        wih[2][cc] = W_ih[2 * H_DIM + j];
        bc[0][cc]  = b_ih[j] + b_hh[j];
        bc[1][cc]  = b_ih[H_DIM + j] + b_hh[H_DIM + j];
        bihn[cc]   = b_ih[2 * H_DIM + j];
        bhhn[cc]   = b_hh[2 * H_DIM + j];
    }
    for (int i = tid; i < TB * H_DIM; i += 256) (&hbuf[0][0][0])[i] = 0.0f;
    float h_own[8][4];
#pragma unroll
    for (int rr = 0; rr < 8; ++rr)
#pragma unroll
        for (int cc = 0; cc < 4; ++cc) h_own[rr][cc] = 0.0f;
    __syncthreads();

    int p = 0;
    for (int t = 0; t < S_LEN; ++t) {
        float xv[8];
#pragma unroll
        for (int rr = 0; rr < 8; ++rr)
            xv[rr] = x[(size_t)(row0 + myrow + rr) * S_LEN + t];

        float acc[3][8][4];
#pragma unroll
        for (int rr = 0; rr < 8; ++rr)
#pragma unroll
            for (int cc = 0; cc < 4; ++cc) {
                acc[0][rr][cc] = fmaf(xv[rr], wih[0][cc], bc[0][cc]);
                acc[1][rr][cc] = fmaf(xv[rr], wih[1][cc], bc[1][cc]);
                acc[2][rr][cc] = bhhn[cc];
            }
        const float* hb = &hbuf[p][0][0];
        for (int k = 0; k < H_DIM; k += 4) {
            float4 hv[8];
#pragma unroll
            for (int rr = 0; rr < 8; ++rr)
                hv[rr] = *(const float4*)(hb + (myrow + rr) * H_DIM + k);
#pragma unroll
            for (int g = 0; g < 3; ++g)
#pragma unroll
                for (int kk = 0; kk < 4; ++kk) {
                    float wrow[4];
#pragma unroll
                    for (int cc = 0; cc < 4; ++cc)
                        wrow[cc] = Whh[(size_t)(g * H_DIM + c0 + cc) * H_DIM + k + kk];
#pragma unroll
                    for (int rr = 0; rr < 8; ++rr) {
                        const float hvv = (&hv[rr].x)[kk];
#pragma unroll
                        for (int cc = 0; cc < 4; ++cc)
                            acc[g][rr][cc] = fmaf(hvv, wrow[cc], acc[g][rr][cc]);
                    }
                }
        }
#pragma unroll
        for (int rr = 0; rr < 8; ++rr) {
            float4 hnew;
#pragma unroll
            for (int cc = 0; cc < 4; ++cc) {
                const float r_  = sigmoid_fast(acc[0][rr][cc]);
                const float z_  = sigmoid_fast(acc[1][rr][cc]);
                const float i_n = fmaf(xv[rr], wih[2][cc], bihn[cc]);
                const float n_  = tanh_fast(fmaf(r_, acc[2][rr][cc], i_n));
                const float hv2 = (1.0f - z_) * n_ + z_ * h_own[rr][cc];
                h_own[rr][cc] = hv2;
                (&hnew.x)[cc] = hv2;
            }
            *(float4*)&hbuf[1 - p][myrow + rr][c0] = hnew;
        }
        __syncthreads();
        p ^= 1;
    }

    const int  pA   = cid;
    const int  pB   = 64 + cid;
    const bool hasB = (cid < 32);
    float accA[8], accB[8];
#pragma unroll
    for (int rr = 0; rr < 8; ++rr) { accA[rr] = 0.0f; accB[rr] = 0.0f; }
    for (int k = 0; k < H_DIM; k += 4) {
        float4 hv[8];
#pragma unroll
        for (int rr = 0; rr < 8; ++rr)
            hv[rr] = *(const float4*)&hbuf[p][myrow + rr][k];
        float wA[4], wB[4];
#pragma unroll
        for (int kk = 0; kk < 4; ++kk) {
            wA[kk] = Wout[(size_t)pA * H_DIM + k + kk];
            wB[kk] = hasB ? Wout[(size_t)pB * H_DIM + k + kk] : 0.0f;
        }
#pragma unroll
        for (int kk = 0; kk < 4; ++kk)
#pragma unroll
            for (int rr = 0; rr < 8; ++rr) {
                const float hvv = (&hv[rr].x)[kk];
                accA[rr] = fmaf(hvv, wA[kk], accA[rr]);
                accB[rr] = fmaf(hvv, wB[kk], accB[rr]);
            }
    }
    const float boA = b_out[pA];
    const float boB = hasB ? b_out[pB] : 0.0f;
#pragma unroll
    for (int rr = 0; rr < 8; ++rr) {
        const size_t orow = (size_t)(row0 + myrow + rr) * P_DIM;
        out[orow + pA] = accA[rr] + boA;
        if (hasB) out[orow + pB] = accB[rr] + boB;
    }
}

extern "C" void kernel_launch(void* const* d_in, const int* in_sizes, int n_in,
                              void* d_out, int out_size, void* d_ws, size_t ws_size,
                              hipStream_t stream) {
    const float* x     = (const float*)d_in[0];
    const float* W_ih  = (const float*)d_in[1];
    const float* W_hh  = (const float*)d_in[2];
    const float* b_ih  = (const float*)d_in[3];
    const float* b_hh  = (const float*)d_in[4];
    const float* W_out = (const float*)d_in[5];
    const float* b_out = (const float*)d_in[6];
    float* out = (float*)d_out;

    const size_t bpack_elems = 8 * 48 * 64 * 8;          // 196608 f16 per matrix
    const size_t wot_elems   = (size_t)H_DIM * P_DIM;    // 24576 fp32
    const size_t ctr_off = bpack_elems * 2 * sizeof(unsigned short) * 2 +
                           wot_elems * sizeof(float);    // 1671168 B (16-aligned)
    const size_t need = ctr_off + sizeof(unsigned int);

    if (ws_size >= need) {
        unsigned short* Bh = (unsigned short*)d_ws;
        unsigned short* Bl = Bh + bpack_elems * 2;
        float* WoT = (float*)(Bl + bpack_elems * 2);
        unsigned int* ctr = (unsigned int*)((char*)d_ws + ctr_off);
        pack_weights<<<G3, H_DIM, 0, stream>>>(W_hh, W_out, Bh, Bl, WoT, ctr);
        gru_mfma<<<B_ROWS / TB, 512, 0, stream>>>(x, W_ih, b_ih, b_hh,
                                                  Bh, Bl, WoT, b_out, out, ctr);
    } else {
        gru_fallback<<<B_ROWS / TB, 256, 0, stream>>>(x, W_ih, W_hh, b_ih, b_hh,
                                                      W_out, b_out, out);
    }
}

// Round 7
// 3484.761 us; speedup vs baseline: 1.4980x; 1.3603x over previous
//
#include <hip/hip_runtime.h>
#include <math.h>

// Problem constants
#define B_ROWS 8192
#define S_LEN  512
#define H_DIM  256
#define G3     768          // 3*H
#define P_DIM  96
#define TB     32           // batch rows per block

typedef __attribute__((ext_vector_type(8))) _Float16 half8;  // 8 f16 (4 VGPRs)
typedef __attribute__((ext_vector_type(4))) float floatx4;   // MFMA C/D frag

__device__ __forceinline__ float sigmoid_fast(float v) {
    return 1.0f / (1.0f + __expf(-v));
}
__device__ __forceinline__ float tanh_fast(float v) {
    return 1.0f - 2.0f / (__expf(2.0f * v) + 1.0f);
}
__device__ __forceinline__ unsigned short f32_f16(float f) {
    _Float16 h = (_Float16)f;                 // RTN
    return __builtin_bit_cast(unsigned short, h);
}
// Involutive 6-bit lane rotation: spreads scatter dest-lanes across bank groups.
__device__ __forceinline__ int rot3(int l) { return ((l << 3) | (l >> 3)) & 63; }

// -------- One-time weight pack: W_hh -> per-lane MFMA B-fragments (hi/lo fp16).
// h in (-1,1) is sent as SINGLE fp16.  W precision policy (round 7):
//   streamed kc=0..5 (k=0..191): SINGLE fp16 hi only (~2^-12 rel error;
//     per-preactivation rms ~3e-5 -> inside demonstrated absmax headroom)
//   kc=6 (LDS cache) and kc=7 (registers): split hi+lo (~2^-22 capture)
// B[k][n] = W_hh[n][k].  16x16x32 B-frag: lane holds B[n=lane&15][k=quad*8+j].
// Tile index = (k>>5)*48 + (j>>4); lane = (j&15) | (((k>>3)&3)<<4); short = k&7.
// Also WoT[k][p] = W_out[p][k]; also zeroes the phase-sync counter.
__global__ void pack_weights(const float* __restrict__ W_hh,
                             const float* __restrict__ W_out,
                             unsigned short* __restrict__ Bh,
                             unsigned short* __restrict__ Bl,
                             float* __restrict__ WoT,
                             unsigned int* __restrict__ ctr) {
    const int j = blockIdx.x;    // gate col 0..767
    const int k = threadIdx.x;   // h idx   0..255
    const float wv = W_hh[j * H_DIM + k];
    const unsigned short hi = f32_f16(wv);
    const float hf = (float)__builtin_bit_cast(_Float16, hi);
    const unsigned short lo = f32_f16(wv - hf);
    const int idx = (((k >> 5) * 48 + (j >> 4)) * 64 +
                     ((j & 15) | (((k >> 3) & 3) << 4))) * 8 + (k & 7);
    Bh[idx] = hi;
    Bl[idx] = lo;
    if (j < P_DIM) WoT[k * P_DIM + j] = W_out[j * H_DIM + k];
    if (j == 0 && k == 0) *ctr = 0u;   // d_ws is re-poisoned every launch
}

// LDS layout (132 KiB total):
//   [0,       32768)  A-fragments (fp16), double-buffered:
//                     buf*16384 + chunk(kc*2+mt)*1024 + slot*16 + short*2
//                     (slot = rot3'd fragment-lane index)
//   [32768,   36864)  xtile[2][32][16] fp32
//   [36864,  135168)  W cache: 96 tiles x 1 KiB = kc=6 hi (slots 0..47,
//                     index T=(gh>>1)*16+w*2+(gh&1)) and kc=6 lo (48..95)
#define A_OFF   0
#define X_OFF   32768
#define W_OFF   36864
#define LDS_SZ  135168

__device__ __forceinline__ void mfma2(floatx4& c0, floatx4& c1,
                                      const half8& a0, const half8& a1,
                                      const half8& bh, const half8& bl) {
    c0 = __builtin_amdgcn_mfma_f32_16x16x32_f16(a0, bh, c0, 0, 0, 0);
    c1 = __builtin_amdgcn_mfma_f32_16x16x32_f16(a1, bh, c1, 0, 0, 0);
    c0 = __builtin_amdgcn_mfma_f32_16x16x32_f16(a0, bl, c0, 0, 0, 0);
    c1 = __builtin_amdgcn_mfma_f32_16x16x32_f16(a1, bl, c1, 0, 0, 0);
}

// Issue 6 streamed hi-tile loads for one kc (stay in flight until MFMA use).
__device__ __forceinline__ void gissue1(half8 (&BH)[6],
                                        const unsigned short* (&pbh)[6],
                                        int kc) {
#pragma unroll
    for (int gh = 0; gh < 6; ++gh)
        BH[gh] = *(const half8*)(pbh[gh] + (size_t)kc * 24576);
}

__device__ __forceinline__ void ahread(half8 (&AH)[2], const char* Ac,
                                       int kc, int rl) {
#pragma unroll
    for (int mt = 0; mt < 2; ++mt)
        AH[mt] = *(const half8*)(Ac + (kc * 2 + mt) * 1024 + rl * 16);
}

// Single-precision kc block: 12 MFMAs (hi product only).
__device__ __forceinline__ void kcmfma1(floatx4 (&acc)[3][2][2],
                                        const half8 (&AH)[2],
                                        const half8 (&BH)[6]) {
#pragma unroll
    for (int gh = 0; gh < 6; ++gh) {
        floatx4& c0 = acc[gh >> 1][0][gh & 1];
        floatx4& c1 = acc[gh >> 1][1][gh & 1];
        c0 = __builtin_amdgcn_mfma_f32_16x16x32_f16(AH[0], BH[gh], c0, 0, 0, 0);
        c1 = __builtin_amdgcn_mfma_f32_16x16x32_f16(AH[1], BH[gh], c1, 0, 0, 0);
    }
}

// Split-precision kc block: 24 MFMAs (hi+lo) — used for kc6 (LDS) and kc7 (regs).
__device__ __forceinline__ void kcmfma(floatx4 (&acc)[3][2][2],
                                       const half8 (&AH)[2],
                                       const half8 (&BH)[6],
                                       const half8 (&BL)[6]) {
#pragma unroll
    for (int gh = 0; gh < 6; ++gh)
        mfma2(acc[gh >> 1][0][gh & 1], acc[gh >> 1][1][gh & 1],
              AH[0], AH[1], BH[gh], BL[gh]);
}

// Main persistent GRU kernel: fp16 single-A MFMA; W single-fp16 for the six
// streamed kc blocks, split hi+lo for the resident kc6/kc7 blocks.
// Halves streamed L2 bytes (590->295 KB/CU/step), MFMA/wave 192->120,
// gissue address VALU, and pipeline registers vs round 6.
// grid = 256 (1 block/CU, forced by 132 KiB LDS), block = 512 (8 waves).
__global__ __launch_bounds__(512, 2)
void gru_mfma(const float* __restrict__ x,
              const float* __restrict__ W_ih,
              const float* __restrict__ b_ih,
              const float* __restrict__ b_hh,
              const unsigned short* __restrict__ Bh,
              const unsigned short* __restrict__ Bl,
              const float* __restrict__ WoT,   // [256][96]
              const float* __restrict__ b_out,
              float* __restrict__ out,
              unsigned int* __restrict__ ctr) {
    __shared__ __align__(16) char smem[LDS_SZ];

    const int tid  = threadIdx.x;
    const int w    = tid >> 6;     // wave 0..7
    const int lane = tid & 63;
    const int q    = lane >> 4;    // quad
    const int c    = lane & 15;
    const int row0 = blockIdx.x * TB;

    // Per-thread gate params; col = 256*g + 32*w + 16*ht + c
    float wih[3][2], bcc[2][2], bihn[2], bhhn[2];
#pragma unroll
    for (int g = 0; g < 3; ++g)
#pragma unroll
        for (int ht = 0; ht < 2; ++ht) {
            const int col = g * H_DIM + w * 32 + ht * 16 + c;
            wih[g][ht] = W_ih[col];
            if (g < 2) {
                bcc[g][ht] = b_ih[col] + b_hh[col];
            } else {
                bihn[ht] = b_ih[col];
                bhhn[ht] = b_hh[col];
            }
        }

    // Streamed-tile base pointers (per wave/lane), gh = g*2 + ht.
    const unsigned short* pbh[6];
    const unsigned short* pbl[6];
#pragma unroll
    for (int gh = 0; gh < 6; ++gh) {
        const size_t toff = (size_t)((gh >> 1) * 16 + w * 2 + (gh & 1)) * 512 + lane * 8;
        pbh[gh] = Bh + toff;
        pbl[gh] = Bl + toff;
    }

    // Register-resident weight tiles: kc=7 hi+lo.  (48 VGPRs)
    half8 r7h[6], r7l[6];
#pragma unroll
    for (int gh = 0; gh < 6; ++gh) {
        r7h[gh] = *(const half8*)(pbh[gh] + 7 * 24576);
        r7l[gh] = *(const half8*)(pbl[gh] + 7 * 24576);
    }

    // LDS weight cache staging: 96 tiles = kc=6 hi (0..47) + kc=6 lo (48..95).
    for (int i = tid; i < 96 * 64; i += 512) {
        const int slot = i >> 6, l16 = i & 63;
        const unsigned short* src = (slot < 48)
            ? (Bh + (size_t)(288 + slot) * 512 + l16 * 8)
            : (Bl + (size_t)(288 + slot - 48) * 512 + l16 * 8);
        *(uint4*)(smem + W_OFF + slot * 1024 + l16 * 16) = *(const uint4*)src;
    }

    // Zero both A-frag buffers (h0 = 0) and stage x for t=0..15.
    for (int i = tid; i < 8192; i += 512) ((int*)(smem + A_OFF))[i] = 0;
    float* xt = (float*)(smem + X_OFF);
    {
        const int r = tid >> 4, t2 = tid & 15;
        xt[r * 16 + t2] = x[(size_t)(row0 + r) * S_LEN + t2];
    }
    __syncthreads();

    // h_old in C-frag layout: element (mt,ht,reg) = h[4q+reg+16mt][32w+16ht+c]
    float h_own[2][2][4];
#pragma unroll
    for (int mt = 0; mt < 2; ++mt)
#pragma unroll
        for (int ht = 0; ht < 2; ++ht)
#pragma unroll
            for (int r = 0; r < 4; ++r) h_own[mt][ht][r] = 0.0f;

    const int rl = rot3(lane);

    // Loop-invariant precompute: scatter byte offsets (within a chunk) for
    // each (ht,r), x-tile row offsets for each (mt,r), kc6 LDS tile bases.
    int soff[2][4];                 // [ht][r] -> rot3(d)*16 + (c&7)*2
#pragma unroll
    for (int ht = 0; ht < 2; ++ht)
#pragma unroll
        for (int r = 0; r < 4; ++r) {
            const int d = (q * 4 + r) | ((2 * ht + (c >> 3)) << 4);
            soff[ht][r] = rot3(d) * 16 + (c & 7) * 2;
        }
    int xbase[2][4];                // [mt][r] -> (q*4+r+16mt)*16
#pragma unroll
    for (int mt = 0; mt < 2; ++mt)
#pragma unroll
        for (int r = 0; r < 4; ++r)
            xbase[mt][r] = (q * 4 + r + 16 * mt) * 16;
    const char* w6base[6];          // kc6 hi tile; lo = +48 KiB
#pragma unroll
    for (int gh = 0; gh < 6; ++gh) {
        const int T = (gh >> 1) * 16 + w * 2 + (gh & 1);
        w6base[gh] = smem + W_OFF + T * 1024 + lane * 16;
    }

    // Pipeline buffers (static names only — rule: no runtime indexing).
    half8 b0h[6], b1h[6];
    half8 ahA[2], ahB[2];

    // Prologue: kc=0 of step 0 in flight before the loop.
    gissue1(b0h, pbh, 0);

#pragma unroll 1
    for (int t = 0; t < S_LEN; ++t) {
        // Defeat LICM of the (t-invariant) streamed loads: make the stream
        // pointers opaque each iteration so loads stay inside the loop.
#pragma unroll
        for (int gh = 0; gh < 6; ++gh)
            asm volatile("" : "+v"(pbh[gh]));

        const int cur = t & 1, nxt = cur ^ 1;
        const char* Ac = smem + A_OFF + cur * 16384;

        ahread(ahA, Ac, 0, rl);            // A-frags for kc=0
        gissue1(b1h, pbh, 1);              // kc=1 stream in flight

        // x for my 8 rows (LDS broadcast); xidx is wave-uniform per step.
        const int xidx = ((t >> 4) & 1) * 512 + (t & 15);
        float xr[2][4];
#pragma unroll
        for (int mt = 0; mt < 2; ++mt)
#pragma unroll
            for (int r = 0; r < 4; ++r)
                xr[mt][r] = xt[xbase[mt][r] + xidx];

        // C frags [gate][mt][ht]; fold x-side pre-activation + bias into init.
        floatx4 acc[3][2][2];
#pragma unroll
        for (int mt = 0; mt < 2; ++mt)
#pragma unroll
            for (int ht = 0; ht < 2; ++ht)
#pragma unroll
                for (int r = 0; r < 4; ++r) {
                    acc[0][mt][ht][r] = fmaf(xr[mt][r], wih[0][ht], bcc[0][ht]);
                    acc[1][mt][ht][r] = fmaf(xr[mt][r], wih[1][ht], bcc[1][ht]);
                    acc[2][mt][ht][r] = bhhn[ht];
                }

        // ---- Pipelined kc ladder (single-fp16 stream): consume kc,
        //      stream kc+1, read A(kc+1) ----
        ahread(ahB, Ac, 1, rl);
        kcmfma1(acc, ahA, b0h);                           // kc0
        gissue1(b0h, pbh, 2);
        ahread(ahA, Ac, 2, rl);
        kcmfma1(acc, ahB, b1h);                           // kc1
        gissue1(b1h, pbh, 3);
        ahread(ahB, Ac, 3, rl);
        kcmfma1(acc, ahA, b0h);                           // kc2
        gissue1(b0h, pbh, 4);
        ahread(ahA, Ac, 4, rl);
        kcmfma1(acc, ahB, b1h);                           // kc3
        gissue1(b1h, pbh, 5);
        ahread(ahB, Ac, 5, rl);
        kcmfma1(acc, ahA, b0h);                           // kc4
        ahread(ahA, Ac, 6, rl);
        kcmfma1(acc, ahB, b1h);                           // kc5

        // ---- kc6: hi+lo from the LDS cache (split precision) ----
        {
            half8 w6h[6], w6l[6];
#pragma unroll
            for (int gh = 0; gh < 6; ++gh) {
                w6h[gh] = *(const half8*)(w6base[gh]);
                w6l[gh] = *(const half8*)(w6base[gh] + 48 * 1024);
            }
            ahread(ahB, Ac, 7, rl);
            kcmfma(acc, ahA, w6h, w6l);                   // kc6
        }

        // Prefetch next step's kc0 while kc7 + gates + barrier run
        // (weights are t-invariant: same addresses every step, no guard).
        gissue1(b0h, pbh, 0);
        kcmfma(acc, ahB, r7h, r7l);                       // kc7 (split)

        // Gates + h update (in-register); scatter next A-frags (rot3-swizzled).
        char* Anx = smem + A_OFF + nxt * 16384;
#pragma unroll
        for (int mt = 0; mt < 2; ++mt) {
            char* ch = Anx + (w * 2 + mt) * 1024;         // chunk kc=w
#pragma unroll
            for (int ht = 0; ht < 2; ++ht)
#pragma unroll
                for (int r = 0; r < 4; ++r) {
                    const float rr  = sigmoid_fast(acc[0][mt][ht][r]);
                    const float zz  = sigmoid_fast(acc[1][mt][ht][r]);
                    const float inn = fmaf(xr[mt][r], wih[2][ht], bihn[ht]);
                    const float nn  = tanh_fast(fmaf(rr, acc[2][mt][ht][r], inn));
                    const float hv  = (1.0f - zz) * nn + zz * h_own[mt][ht][r];
                    h_own[mt][ht][r] = hv;
                    *(unsigned short*)(ch + soff[ht][r]) = f32_f16(hv);
                }
        }

        // Re-stage x for the next 16 steps (into the idle x buffer).
        const bool tick = ((t & 15) == 15) && (t != S_LEN - 1);
        if (tick) {
            const int r = tid >> 4, t2 = tid & 15;
            xt[((((t + 1) >> 4) & 1) * 32 + r) * 16 + t2] =
                x[(size_t)(row0 + r) * S_LEN + (t + 1) + t2];
        }
        __syncthreads();   // single barrier: next A-frags + x tile visible

        // Phase-alignment heartbeat every 16 steps: keeps all 256 blocks'
        // weight streams in phase so the per-XCD L2 working set stays hot.
        // Pure timing hint — bounded spin, no data dependency, no fences.
        if (tick) {
            if (tid == 0) {
                const unsigned int tgt = 256u * (unsigned)((t >> 4) + 1);
                atomicAdd(ctr, 1u);
                for (int spin = 0; spin < (1 << 17); ++spin) {
                    if (__hip_atomic_load(ctr, __ATOMIC_RELAXED,
                                          __HIP_MEMORY_SCOPE_AGENT) >= tgt) break;
                    __builtin_amdgcn_s_sleep(4);
                }
            }
            __syncthreads();
        }
    }

    // -------- Epilogue: dump final h (fp32, from registers) and project.
    float* hfin = (float*)(smem);   // reuse A region: [32][256] = 32 KiB
#pragma unroll
    for (int mt = 0; mt < 2; ++mt)
#pragma unroll
        for (int ht = 0; ht < 2; ++ht)
#pragma unroll
            for (int r = 0; r < 4; ++r) {
                const int m = q * 4 + r + 16 * mt;
                const int k = w * 32 + ht * 16 + c;
                hfin[m * H_DIM + k] = h_own[mt][ht][r];
            }
    __syncthreads();

    if (tid < 256) {
        const int cid   = tid & 63;
        const int rid   = tid >> 6;
        const int myrow = rid * 8;
        const int pA    = cid;
        const int pB    = 64 + cid;
        const bool hasB = (cid < 32);
        float accA[8], accB[8];
#pragma unroll
        for (int rr = 0; rr < 8; ++rr) { accA[rr] = 0.0f; accB[rr] = 0.0f; }

        for (int k = 0; k < H_DIM; k += 4) {
            float4 hv[8];
#pragma unroll
            for (int rr = 0; rr < 8; ++rr)
                hv[rr] = *(const float4*)&hfin[(myrow + rr) * H_DIM + k];
            float wA[4], wB[4];
#pragma unroll
            for (int kk = 0; kk < 4; ++kk) {
                wA[kk] = WoT[(size_t)(k + kk) * P_DIM + pA];
                wB[kk] = hasB ? WoT[(size_t)(k + kk) * P_DIM + pB] : 0.0f;
            }
#pragma unroll
            for (int kk = 0; kk < 4; ++kk)
#pragma unroll
                for (int rr = 0; rr < 8; ++rr) {
                    const float hvv = (&hv[rr].x)[kk];
                    accA[rr] = fmaf(hvv, wA[kk], accA[rr]);
                    accB[rr] = fmaf(hvv, wB[kk], accB[rr]);
                }
        }
        const float boA = b_out[pA];
        const float boB = hasB ? b_out[pB] : 0.0f;
#pragma unroll
        for (int rr = 0; rr < 8; ++rr) {
            const size_t orow = (size_t)(row0 + myrow + rr) * P_DIM;
            out[orow + pA] = accA[rr] + boA;
            if (hasB) out[orow + pB] = accB[rr] + boB;
        }
    }
}

// -------- fp32 fallback — used only if ws_size is too small.
__global__ __launch_bounds__(256, 1)
void gru_fallback(const float* __restrict__ x,
                  const float* __restrict__ W_ih,
                  const float* __restrict__ Whh,
                  const float* __restrict__ b_ih,
                  const float* __restrict__ b_hh,
                  const float* __restrict__ Wout,
                  const float* __restrict__ b_out,
                  float* __restrict__ out) {
    __shared__ float hbuf[2][TB][H_DIM];

    const int tid   = threadIdx.x;
    const int cid   = tid & 63;
    const int rid   = tid >> 6;
    const int row0  = blockIdx.x * TB;
    const int myrow = rid * 8;
    const int c0    = cid * 4;

    float wih[3][4], bc[2][4], bihn[4], bhhn[4];
#pragma unroll
    for (int cc = 0; cc < 4; ++cc) {
        const int j = c0 + cc;
        wih[0][cc] = W_ih[j];
        wih[1][cc] = W_ih[H_DIM + j];
        wih[2][cc] = W_ih[2 * H_DIM + j];
        bc[0][cc]  = b_ih[j] + b_hh[j];
        bc[1][cc]  = b_ih[H_DIM + j] + b_hh[H_DIM + j];
        bihn[cc]   = b_ih[2 * H_DIM + j];
        bhhn[cc]   = b_hh[2 * H_DIM + j];
    }
    for (int i = tid; i < TB * H_DIM; i += 256) (&hbuf[0][0][0])[i] = 0.0f;
    float h_own[8][4];
#pragma unroll
    for (int rr = 0; rr < 8; ++rr)
#pragma unroll
        for (int cc = 0; cc < 4; ++cc) h_own[rr][cc] = 0.0f;
    __syncthreads();

    int p = 0;
    for (int t = 0; t < S_LEN; ++t) {
        float xv[8];
#pragma unroll
        for (int rr = 0; rr < 8; ++rr)
            xv[rr] = x[(size_t)(row0 + myrow + rr) * S_LEN + t];

        float acc[3][8][4];
#pragma unroll
        for (int rr = 0; rr < 8; ++rr)
#pragma unroll
            for (int cc = 0; cc < 4; ++cc) {
                acc[0][rr][cc] = fmaf(xv[rr], wih[0][cc], bc[0][cc]);
                acc[1][rr][cc] = fmaf(xv[rr], wih[1][cc], bc[1][cc]);
                acc[2][rr][cc] = bhhn[cc];
            }
        const float* hb = &hbuf[p][0][0];
        for (int k = 0; k < H_DIM; k += 4) {
            float4 hv[8];
#pragma unroll
            for (int rr = 0; rr < 8; ++rr)
                hv[rr] = *(const float4*)(hb + (myrow + rr) * H_DIM + k);
#pragma unroll
            for (int g = 0; g < 3; ++g)
#pragma unroll
                for (int kk = 0; kk < 4; ++kk) {
                    float wrow[4];
#pragma unroll
                    for (int cc = 0; cc < 4; ++cc)
                        wrow[cc] = Whh[(size_t)(g * H_DIM + c0 + cc) * H_DIM + k + kk];
#pragma unroll
                    for (int rr = 0; rr < 8; ++rr) {
                        const float hvv = (&hv[rr].x)[kk];
#pragma unroll
                        for (int cc = 0; cc < 4; ++cc)
                            acc[g][rr][cc] = fmaf(hvv, wrow[cc], acc[g][rr][cc]);
                    }
                }
        }
#pragma unroll
        for (int rr = 0; rr < 8; ++rr) {
            float4 hnew;
#pragma unroll
            for (int cc = 0; cc < 4; ++cc) {
                const float r_  = sigmoid_fast(acc[0][rr][cc]);
                const float z_  = sigmoid_fast(acc[1][rr][cc]);
                const float i_n = fmaf(xv[rr], wih[2][cc], bihn[cc]);
                const float n_  = tanh_fast(fmaf(r_, acc[2][rr][cc], i_n));
                const float hv2 = (1.0f - z_) * n_ + z_ * h_own[rr][cc];
                h_own[rr][cc] = hv2;
                (&hnew.x)[cc] = hv2;
            }
            *(float4*)&hbuf[1 - p][myrow + rr][c0] = hnew;
        }
        __syncthreads();
        p ^= 1;
    }

    const int  pA   = cid;
    const int  pB   = 64 + cid;
    const bool hasB = (cid < 32);
    float accA[8], accB[8];
#pragma unroll
    for (int rr = 0; rr < 8; ++rr) { accA[rr] = 0.0f; accB[rr] = 0.0f; }
    for (int k = 0; k < H_DIM; k += 4) {
        float4 hv[8];
#pragma unroll
        for (int rr = 0; rr < 8; ++rr)
            hv[rr] = *(const float4*)&hbuf[p][myrow + rr][k];
        float wA[4], wB[4];
#pragma unroll
        for (int kk = 0; kk < 4; ++kk) {
            wA[kk] = Wout[(size_t)pA * H_DIM + k + kk];
            wB[kk] = hasB ? Wout[(size_t)pB * H_DIM + k + kk] : 0.0f;
        }
#pragma unroll
        for (int kk = 0; kk < 4; ++kk)
#pragma unroll
            for (int rr = 0; rr < 8; ++rr) {
                const float hvv = (&hv[rr].x)[kk];
                accA[rr] = fmaf(hvv, wA[kk], accA[rr]);
                accB[rr] = fmaf(hvv, wB[kk], accB[rr]);
            }
    }
    const float boA = b_out[pA];
    const float boB = hasB ? b_out[pB] : 0.0f;
#pragma unroll
    for (int rr = 0; rr < 8; ++rr) {
        const size_t orow = (size_t)(row0 + myrow + rr) * P_DIM;
        out[orow + pA] = accA[rr] + boA;
        if (hasB) out[orow + pB] = accB[rr] + boB;
    }
}

extern "C" void kernel_launch(void* const* d_in, const int* in_sizes, int n_in,
                              void* d_out, int out_size, void* d_ws, size_t ws_size,
                              hipStream_t stream) {
    const float* x     = (const float*)d_in[0];
    const float* W_ih  = (const float*)d_in[1];
    const float* W_hh  = (const float*)d_in[2];
    const float* b_ih  = (const float*)d_in[3];
    const float* b_hh  = (const float*)d_in[4];
    const float* W_out = (const float*)d_in[5];
    const float* b_out = (const float*)d_in[6];
    float* out = (float*)d_out;

    const size_t bpack_elems = 8 * 48 * 64 * 8;          // 196608 f16 per matrix
    const size_t wot_elems   = (size_t)H_DIM * P_DIM;    // 24576 fp32
    const size_t ctr_off = bpack_elems * 2 * sizeof(unsigned short) * 2 +
                           wot_elems * sizeof(float);    // 1671168 B (16-aligned)
    const size_t need = ctr_off + sizeof(unsigned int);

    if (ws_size >= need) {
        unsigned short* Bh = (unsigned short*)d_ws;
        unsigned short* Bl = Bh + bpack_elems * 2;
        float* WoT = (float*)(Bl + bpack_elems * 2);
        unsigned int* ctr = (unsigned int*)((char*)d_ws + ctr_off);
        pack_weights<<<G3, H_DIM, 0, stream>>>(W_hh, W_out, Bh, Bl, WoT, ctr);
        gru_mfma<<<B_ROWS / TB, 512, 0, stream>>>(x, W_ih, b_ih, b_hh,
                                                  Bh, Bl, WoT, b_out, out, ctr);
    } else {
        gru_fallback<<<B_ROWS / TB, 256, 0, stream>>>(x, W_ih, W_hh, b_ih, b_hh,
                                                      W_out, b_out, out);
    }
}